// Round 1
// baseline (1326.389 us; speedup 1.0000x reference)
//
#include <hip/hip_runtime.h>
#include <hip/hip_bf16.h>
#include <math.h>

// MAGNN-style hetero-GAT forward, fp32 baseline.
// Pipeline: typed transform GEMM (scatter rows) -> per metapath:
//   w_att = Wr^T a (tiny), fused gather-mean + edge score + target histogram,
//   CSR build (scan+scatter), per-target segment softmax + weighted feature sum,
//   per-head 128x128 GEMM + elu, semantic tanh-GEMM reduced to a scalar.
// Then betas (softmax of means), combine, output projection.

#define HIDDEN 128
#define HEADS 4
#define NTGT 8192
#define NEDGE 100000
#define NNODES 100000

// ---------------- w_att[h,k] = sum_d a[h,d] * Wr[h*128+d, k] ----------------
__global__ __launch_bounds__(256)
void watt_kernel(const float* __restrict__ Wr, const float* __restrict__ a,
                 float* __restrict__ watt)
{
    int idx = blockIdx.x * 256 + threadIdx.x;
    if (idx >= HEADS * HIDDEN) return;
    int h = idx >> 7, k = idx & 127;
    float s = 0.f;
    #pragma unroll 4
    for (int d = 0; d < HIDDEN; ++d)
        s += a[h * HIDDEN + d] * Wr[(size_t)(h * HIDDEN + d) * HIDDEN + k];
    watt[idx] = s;
}

// ------- gather-mean + edge score + histogram: 1 wave per edge --------------
__global__ __launch_bounds__(256)
void gather_kernel(const float* __restrict__ tf, const int* __restrict__ eidx,
                   const int* __restrict__ etgt, const float* __restrict__ watt,
                   float* __restrict__ hfeat, float* __restrict__ esc,
                   int* __restrict__ cnt, int E)
{
    __shared__ float sw[HEADS * HIDDEN];
    for (int i = threadIdx.x; i < HEADS * HIDDEN; i += 256) sw[i] = watt[i];
    __syncthreads();
    int wave = threadIdx.x >> 6;
    int lane = threadIdx.x & 63;
    int e = blockIdx.x * 4 + wave;
    if (e >= E) return;
    int i0 = eidx[e * 3 + 0], i1 = eidx[e * 3 + 1], i2 = eidx[e * 3 + 2];
    const float inv3 = 1.f / 3.f;
    float v0 = (tf[(size_t)i0 * 128 + lane] + tf[(size_t)i1 * 128 + lane] +
                tf[(size_t)i2 * 128 + lane]) * inv3;
    float v1 = (tf[(size_t)i0 * 128 + 64 + lane] + tf[(size_t)i1 * 128 + 64 + lane] +
                tf[(size_t)i2 * 128 + 64 + lane]) * inv3;
    hfeat[(size_t)e * 128 + lane] = v0;
    hfeat[(size_t)e * 128 + 64 + lane] = v1;
    #pragma unroll
    for (int h = 0; h < HEADS; ++h) {
        float p = v0 * sw[h * 128 + lane] + v1 * sw[h * 128 + 64 + lane];
        #pragma unroll
        for (int o = 32; o; o >>= 1) p += __shfl_xor(p, o, 64);
        if (lane == 0) esc[(size_t)e * 4 + h] = (p >= 0.f) ? p : 0.2f * p;
    }
    if (lane == 0) atomicAdd(&cnt[etgt[e]], 1);
}

// ---------------- exclusive scan of cnt[8192] -> rowptr; zero cnt -----------
__global__ __launch_bounds__(256)
void scan_kernel(int* __restrict__ cnt, int* __restrict__ rowptr)
{
    __shared__ int part[256];
    int t = threadIdx.x;
    int vals[32];
    int s = 0;
    int base = t * 32;
    #pragma unroll
    for (int i = 0; i < 32; ++i) { vals[i] = cnt[base + i]; s += vals[i]; }
    part[t] = s;
    __syncthreads();
    for (int o = 1; o < 256; o <<= 1) {
        int v = (t >= o) ? part[t - o] : 0;
        __syncthreads();
        part[t] += v;
        __syncthreads();
    }
    int off = (t == 0) ? 0 : part[t - 1];
    #pragma unroll
    for (int i = 0; i < 32; ++i) { rowptr[base + i] = off; off += vals[i]; cnt[base + i] = 0; }
    if (t == 255) rowptr[NTGT] = off;
}

__global__ __launch_bounds__(256)
void scatter_kernel(const int* __restrict__ etgt, const int* __restrict__ rowptr,
                    int* __restrict__ cur, int* __restrict__ eids, int E)
{
    int e = blockIdx.x * 256 + threadIdx.x;
    if (e < E) {
        int t = etgt[e];
        int pos = atomicAdd(&cur[t], 1);
        eids[rowptr[t] + pos] = e;
    }
}

// ------- per-target segment softmax + weighted sum: 1 wave per target -------
__global__ __launch_bounds__(64)
void seg_kernel(const int* __restrict__ rowptr, const int* __restrict__ eids,
                const float* __restrict__ esc, const float* __restrict__ hfeat,
                float* __restrict__ gn)
{
    int t = blockIdx.x;
    int lane = threadIdx.x;
    int beg = rowptr[t], end = rowptr[t + 1];
    float mx[4] = {-INFINITY, -INFINITY, -INFINITY, -INFINITY};
    for (int i = beg + lane; i < end; i += 64) {
        int e = eids[i];
        #pragma unroll
        for (int h = 0; h < 4; ++h) mx[h] = fmaxf(mx[h], esc[(size_t)e * 4 + h]);
    }
    #pragma unroll
    for (int h = 0; h < 4; ++h) {
        #pragma unroll
        for (int o = 32; o; o >>= 1) mx[h] = fmaxf(mx[h], __shfl_xor(mx[h], o, 64));
    }
    float acc0[4] = {0, 0, 0, 0}, acc1[4] = {0, 0, 0, 0}, den[4] = {0, 0, 0, 0};
    for (int i = beg; i < end; ++i) {   // serial over ~12 edges, all lanes together
        int e = eids[i];
        float f0 = hfeat[(size_t)e * 128 + lane];
        float f1 = hfeat[(size_t)e * 128 + 64 + lane];
        #pragma unroll
        for (int h = 0; h < 4; ++h) {
            float w = __expf(esc[(size_t)e * 4 + h] - mx[h]);
            den[h] += w;
            acc0[h] += w * f0;
            acc1[h] += w * f1;
        }
    }
    #pragma unroll
    for (int h = 0; h < 4; ++h) {
        float d = 1.f / (den[h] + 1e-9f);
        gn[(size_t)t * 512 + h * 128 + lane] = acc0[h] * d;
        gn[(size_t)t * 512 + h * 128 + 64 + lane] = acc1[h] * d;
    }
}

// --------------- generic fp32 C = A * B^T tiled GEMM (128x128x16) ----------
// EPI 0: C[row(m)][n] = acc + bias[n]  (rowmap scatter optional)
// EPI 1: C = elu(acc)
// EPI 2: semantic reduce: atomicAdd(semOut, sum tanh(acc+bias[n])*vs[n])
template<int EPI>
__global__ __launch_bounds__(256)
void gemm_atb(const float* __restrict__ A, int lda, int aOffY,
              const float* __restrict__ B, int ldb, int bOffY,
              const float* __restrict__ bias,
              float* __restrict__ C, int ldc, int cOffY,
              int M, int N, int K,
              const int* __restrict__ rowmap,
              const float* __restrict__ vs,
              float* __restrict__ semOut)
{
    __shared__ __align__(16) float As[16][132];
    __shared__ __align__(16) float Bs[16][132];
    __shared__ float red[256];

    A += (size_t)blockIdx.y * aOffY;
    B += (size_t)blockIdx.y * bOffY;
    C += (size_t)blockIdx.y * cOffY;

    const int m0 = blockIdx.x * 128;
    const int tid = threadIdx.x;
    const int tx = tid & 15, ty = tid >> 4;
    const int lr = tid >> 2;
    const int lk = (tid & 3) << 2;

    float acc[2][2][16];
    #pragma unroll
    for (int i = 0; i < 2; ++i)
        #pragma unroll
        for (int j = 0; j < 2; ++j)
            #pragma unroll
            for (int q = 0; q < 16; ++q) acc[i][j][q] = 0.f;

    for (int k0 = 0; k0 < K; k0 += 16) {
        #pragma unroll
        for (int half = 0; half < 2; ++half) {
            int r = lr + half * 64;
            int gm = m0 + r;
            float4 v = make_float4(0.f, 0.f, 0.f, 0.f);
            if (gm < M) v = *(const float4*)(A + (size_t)gm * lda + k0 + lk);
            As[lk + 0][r] = v.x; As[lk + 1][r] = v.y; As[lk + 2][r] = v.z; As[lk + 3][r] = v.w;
            float4 w = make_float4(0.f, 0.f, 0.f, 0.f);
            if (r < N) w = *(const float4*)(B + (size_t)r * ldb + k0 + lk);
            Bs[lk + 0][r] = w.x; Bs[lk + 1][r] = w.y; Bs[lk + 2][r] = w.z; Bs[lk + 3][r] = w.w;
        }
        __syncthreads();
        #pragma unroll
        for (int k = 0; k < 16; ++k) {
            const float4 a0 = *(const float4*)&As[k][ty * 4];
            const float4 a1 = *(const float4*)&As[k][64 + ty * 4];
            const float4 bv0 = *(const float4*)&Bs[k][tx * 4];
            const float4 bv1 = *(const float4*)&Bs[k][64 + tx * 4];
            const float ar[2][4] = {{a0.x, a0.y, a0.z, a0.w}, {a1.x, a1.y, a1.z, a1.w}};
            const float br[2][4] = {{bv0.x, bv0.y, bv0.z, bv0.w}, {bv1.x, bv1.y, bv1.z, bv1.w}};
            #pragma unroll
            for (int i = 0; i < 2; ++i)
                #pragma unroll
                for (int ii = 0; ii < 4; ++ii)
                    #pragma unroll
                    for (int j = 0; j < 2; ++j)
                        #pragma unroll
                        for (int jj = 0; jj < 4; ++jj)
                            acc[i][j][ii * 4 + jj] += ar[i][ii] * br[j][jj];
        }
        __syncthreads();
    }

    if (EPI == 2) {
        float local = 0.f;
        #pragma unroll
        for (int i = 0; i < 2; ++i)
            #pragma unroll
            for (int ii = 0; ii < 4; ++ii) {
                int gm = m0 + i * 64 + ty * 4 + ii;
                if (gm >= M) continue;
                #pragma unroll
                for (int j = 0; j < 2; ++j)
                    #pragma unroll
                    for (int jj = 0; jj < 4; ++jj) {
                        int n = j * 64 + tx * 4 + jj;
                        if (n < N) local += tanhf(acc[i][j][ii * 4 + jj] + bias[n]) * vs[n];
                    }
            }
        red[tid] = local;
        __syncthreads();
        for (int o = 128; o > 0; o >>= 1) {
            if (tid < o) red[tid] += red[tid + o];
            __syncthreads();
        }
        if (tid == 0) atomicAdd(semOut, red[0]);
        return;
    }

    #pragma unroll
    for (int i = 0; i < 2; ++i)
        #pragma unroll
        for (int ii = 0; ii < 4; ++ii) {
            int gm = m0 + i * 64 + ty * 4 + ii;
            if (gm >= M) continue;
            size_t crow = rowmap ? (size_t)rowmap[gm] : (size_t)gm;
            #pragma unroll
            for (int j = 0; j < 2; ++j)
                #pragma unroll
                for (int jj = 0; jj < 4; ++jj) {
                    int n = j * 64 + tx * 4 + jj;
                    if (n >= N) continue;
                    float v = acc[i][j][ii * 4 + jj];
                    if (EPI == 0 && bias) v += bias[n];
                    if (EPI == 1) v = v > 0.f ? v : expm1f(v);
                    C[crow * (size_t)ldc + n] = v;
                }
        }
}

// ---------------- betas = softmax(s/8192) for a pair ------------------------
__global__ void beta_kernel(const float* __restrict__ s, float* __restrict__ beta)
{
    if (threadIdx.x == 0 && blockIdx.x == 0) {
        float b0 = s[0] * (1.f / 8192.f), b1 = s[1] * (1.f / 8192.f);
        float m = fmaxf(b0, b1);
        float e0 = __expf(b0 - m), e1 = __expf(b1 - m);
        float d = e0 + e1;
        beta[0] = e0 / d;
        beta[1] = e1 / d;
    }
}

// ---------------- out = beta0*h0 + beta1*h1 (in-place safe on h0) ----------
__global__ __launch_bounds__(256)
void combine_kernel(const float* __restrict__ h0, const float* __restrict__ h1,
                    const float* __restrict__ beta, float* __restrict__ out)
{
    int i = blockIdx.x * 256 + threadIdx.x;
    float b0 = beta[0], b1 = beta[1];
    float4 x = ((const float4*)h0)[i];
    float4 y = ((const float4*)h1)[i];
    float4 r;
    r.x = b0 * x.x + b1 * y.x;
    r.y = b0 * x.y + b1 * y.y;
    r.z = b0 * x.z + b1 * y.z;
    r.w = b0 * x.w + b1 * y.w;
    ((float4*)out)[i] = r;
}

extern "C" void kernel_launch(void* const* d_in, const int* in_sizes, int n_in,
                              void* d_out, int out_size, void* d_ws, size_t ws_size,
                              hipStream_t stream)
{
    const float* feat0 = (const float*)d_in[0];
    const float* feat1 = (const float*)d_in[1];
    const int* nidx0 = (const int*)d_in[2];
    const int* nidx1 = (const int*)d_in[3];
    const int* eidx[4] = {(const int*)d_in[4], (const int*)d_in[6],
                          (const int*)d_in[8], (const int*)d_in[10]};
    const int* etgt[4] = {(const int*)d_in[5], (const int*)d_in[7],
                          (const int*)d_in[9], (const int*)d_in[11]};
    const float* W0 = (const float*)d_in[12]; const float* b0 = (const float*)d_in[13];
    const float* W1 = (const float*)d_in[14]; const float* b1 = (const float*)d_in[15];
    const float* Wr[4] = {(const float*)d_in[16], (const float*)d_in[18],
                          (const float*)d_in[25], (const float*)d_in[27]};
    const float* av[4] = {(const float*)d_in[17], (const float*)d_in[19],
                          (const float*)d_in[26], (const float*)d_in[28]};
    const float* Ws[2] = {(const float*)d_in[20], (const float*)d_in[29]};
    const float* bs[2] = {(const float*)d_in[21], (const float*)d_in[30]};
    const float* vsem[2] = {(const float*)d_in[22], (const float*)d_in[31]};
    const float* Wo[2] = {(const float*)d_in[23], (const float*)d_in[32]};
    const float* bo[2] = {(const float*)d_in[24], (const float*)d_in[33]};
    float* out = (float*)d_out;

    // workspace carve (all 256B aligned)
    char* p = (char*)d_ws;
    auto carve = [&](size_t bytes) { char* r = p; p += (bytes + 255) & ~(size_t)255; return r; };
    float* tf    = (float*)carve((size_t)NNODES * 128 * 4);   // 51.2 MB
    float* hfeat = (float*)carve((size_t)NEDGE * 128 * 4);    // 51.2 MB
    float* esc   = (float*)carve((size_t)NEDGE * 4 * 4);      // 1.6 MB
    float* gn    = (float*)carve((size_t)NTGT * 512 * 4);     // 16.8 MB
    float* outp1 = (float*)carve((size_t)NTGT * 512 * 4);     // 16.8 MB
    float* watt  = (float*)carve(HEADS * HIDDEN * 4);
    float* ssem  = (float*)carve(4 * 4);
    float* betab = (float*)carve(4 * 4);
    int* cnt     = (int*)carve((size_t)NTGT * 4);
    int* rowptr  = (int*)carve((size_t)(NTGT + 1) * 4);
    int* eids    = (int*)carve((size_t)NEDGE * 4);

    hipMemsetAsync(tf, 0, (size_t)NNODES * 128 * 4, stream);
    hipMemsetAsync(ssem, 0, 16, stream);

    dim3 blk(256, 1, 1);

    // typed node transform, scattered rows
    gemm_atb<0><<<dim3(391, 1), blk, 0, stream>>>(feat0, 512, 0, W0, 512, 0, b0,
                                                  tf, 128, 0, 50000, 128, 512,
                                                  nidx0, nullptr, nullptr);
    gemm_atb<0><<<dim3(391, 1), blk, 0, stream>>>(feat1, 512, 0, W1, 512, 0, b1,
                                                  tf, 128, 0, 50000, 128, 512,
                                                  nidx1, nullptr, nullptr);

    const size_t LOG_OFF[2] = {0, (size_t)NTGT * 64};
    const size_t H_OFF[2] = {(size_t)NTGT * 64 * 2,
                             (size_t)NTGT * 64 * 2 + (size_t)NTGT * 512};

    for (int nt = 0; nt < 2; ++nt) {
        float* o0 = out + H_OFF[nt];   // reuse d_out h-region as metapath-0 buffer
        float* o1 = outp1;
        for (int pp = 0; pp < 2; ++pp) {
            int mp = nt * 2 + pp;
            float* ob = (pp == 0) ? o0 : o1;
            watt_kernel<<<dim3(2), blk, 0, stream>>>(Wr[mp], av[mp], watt);
            hipMemsetAsync(cnt, 0, (size_t)NTGT * 4, stream);
            gather_kernel<<<dim3(NEDGE / 4), blk, 0, stream>>>(tf, eidx[mp], etgt[mp],
                                                               watt, hfeat, esc, cnt, NEDGE);
            scan_kernel<<<dim3(1), blk, 0, stream>>>(cnt, rowptr);
            scatter_kernel<<<dim3((NEDGE + 255) / 256), blk, 0, stream>>>(etgt[mp], rowptr,
                                                                          cnt, eids, NEDGE);
            seg_kernel<<<dim3(NTGT), dim3(64), 0, stream>>>(rowptr, eids, esc, hfeat, gn);
            // out_p = elu(gn @ Wr^T) per head (grid.y = head)
            gemm_atb<1><<<dim3(64, 4), blk, 0, stream>>>(gn, 512, 128,
                                                         Wr[mp], 128, 128 * 128, nullptr,
                                                         ob, 512, 128, NTGT, 128, 128,
                                                         nullptr, nullptr, nullptr);
            // semantic scalar: sum tanh(out_p @ Ws^T + bs) . vs
            gemm_atb<2><<<dim3(64, 1), blk, 0, stream>>>(ob, 512, 0, Ws[nt], 512, 0, bs[nt],
                                                         nullptr, 0, 0, NTGT, 128, 512,
                                                         nullptr, vsem[nt], ssem + mp);
        }
        beta_kernel<<<dim3(1), dim3(64), 0, stream>>>(ssem + nt * 2, betab + nt * 2);
        combine_kernel<<<dim3(NTGT * 512 / 4 / 256), blk, 0, stream>>>(o0, o1,
                                                                       betab + nt * 2,
                                                                       out + H_OFF[nt]);
        gemm_atb<0><<<dim3(64, 1), blk, 0, stream>>>(out + H_OFF[nt], 512, 0,
                                                     Wo[nt], 512, 0, bo[nt],
                                                     out + LOG_OFF[nt], 64, 0,
                                                     NTGT, 64, 512,
                                                     nullptr, nullptr, nullptr);
    }
}

// Round 2
// 1093.992 us; speedup vs baseline: 1.2124x; 1.2124x over previous
//
#include <hip/hip_runtime.h>
#include <hip/hip_bf16.h>
#include <math.h>

// MAGNN-style hetero-GAT forward.
// R2: all GEMMs moved to bf16 MFMA (fp32 inputs converted inline in registers,
// fp32 accumulate). No LDS staging: A rows are consumed once (N<=128 = single
// tile column), B (<=256KB) stays L2-resident.

#define HIDDEN 128
#define HEADS 4
#define NTGT 8192
#define NEDGE 100000
#define NNODES 100000

typedef __attribute__((ext_vector_type(8))) short bf16x8;
typedef __attribute__((ext_vector_type(4))) float f32x4;

__device__ inline short b16(float f)
{
    union { __hip_bfloat16 h; short s; } u;
    u.h = __float2bfloat16(f);
    return u.s;
}

// load 8 contiguous fp32 at [row][k..k+8) and convert to bf16x8
template<bool CLAMP>
__device__ inline bf16x8 load_frag(const float* __restrict__ base, int row,
                                   int maxrow, int lda, int k)
{
    if (CLAMP) row = min(row, maxrow);
    const float* p = base + (size_t)row * lda + k;
    float4 u = *(const float4*)p;
    float4 v = *(const float4*)(p + 4);
    bf16x8 r;
    r[0] = b16(u.x); r[1] = b16(u.y); r[2] = b16(u.z); r[3] = b16(u.w);
    r[4] = b16(v.x); r[5] = b16(v.y); r[6] = b16(v.z); r[7] = b16(v.w);
    return r;
}

// ---------------- unified MFMA GEMM: C = A(fp32->bf16) * B^T ---------------
// A: [M][K] row-major fp32 (lda); B: [N][K] row-major fp32 (ldb), N = NF*16.
// Block = 256 thr = 4 waves; block tile 128 rows x N cols; wave = 32 rows.
// EPI 0: C[row(m)][n] = acc + bias[n]   (rowmap scatter optional)
// EPI 1: C = elu(acc)
// EPI 2: atomicAdd(semOut, sum tanh(acc+bias[n])*vs[n])   (requires M%128==0)
template<int EPI, int NF>
__global__ __launch_bounds__(256)
void mgemm(const float* __restrict__ A, int lda, int aOffY,
           const float* __restrict__ B, int ldb, int bOffY,
           const float* __restrict__ bias,
           float* __restrict__ C, int ldc, int cOffY,
           int M, int K,
           const int* __restrict__ rowmap,
           const float* __restrict__ vs,
           float* __restrict__ semOut)
{
    __shared__ float red[4];

    A += (size_t)blockIdx.y * aOffY;
    B += (size_t)blockIdx.y * bOffY;
    if (C) C += (size_t)blockIdx.y * cOffY;

    const int tid = threadIdx.x;
    const int w = tid >> 6;
    const int l = tid & 63;
    const int lr = l & 15;          // row within 16-frag
    const int lk = (l >> 4) * 8;    // k offset within 32

    const int m0 = blockIdx.x * 128 + w * 32;

    f32x4 acc[2][NF];
    #pragma unroll
    for (int i = 0; i < 2; ++i)
        #pragma unroll
        for (int j = 0; j < NF; ++j)
            acc[i][j] = (f32x4){0.f, 0.f, 0.f, 0.f};

    for (int k0 = 0; k0 < K; k0 += 32) {
        bf16x8 a0 = load_frag<true>(A, m0 + lr,      M - 1, lda, k0 + lk);
        bf16x8 a1 = load_frag<true>(A, m0 + 16 + lr, M - 1, lda, k0 + lk);
        #pragma unroll
        for (int j = 0; j < NF; ++j) {
            bf16x8 bf = load_frag<false>(B, j * 16 + lr, 0, ldb, k0 + lk);
            acc[0][j] = __builtin_amdgcn_mfma_f32_16x16x32_bf16(a0, bf, acc[0][j], 0, 0, 0);
            acc[1][j] = __builtin_amdgcn_mfma_f32_16x16x32_bf16(a1, bf, acc[1][j], 0, 0, 0);
        }
    }

    if (EPI == 2) {
        float local = 0.f;
        #pragma unroll
        for (int i = 0; i < 2; ++i) {
            int rbase = m0 + i * 16 + (l >> 4) * 4;
            #pragma unroll
            for (int r = 0; r < 4; ++r) {
                if (rbase + r >= M) continue;
                #pragma unroll
                for (int j = 0; j < NF; ++j) {
                    int n = j * 16 + lr;
                    local += tanhf(acc[i][j][r] + bias[n]) * vs[n];
                }
            }
        }
        #pragma unroll
        for (int o = 32; o; o >>= 1) local += __shfl_xor(local, o, 64);
        if (l == 0) red[w] = local;
        __syncthreads();
        if (tid == 0) atomicAdd(semOut, red[0] + red[1] + red[2] + red[3]);
        return;
    }

    #pragma unroll
    for (int i = 0; i < 2; ++i) {
        int rbase = m0 + i * 16 + (l >> 4) * 4;
        #pragma unroll
        for (int r = 0; r < 4; ++r) {
            int gm = rbase + r;
            if (gm >= M) continue;
            size_t crow = rowmap ? (size_t)rowmap[gm] : (size_t)gm;
            #pragma unroll
            for (int j = 0; j < NF; ++j) {
                int n = j * 16 + lr;
                float v = acc[i][j][r];
                if (EPI == 0 && bias) v += bias[n];
                if (EPI == 1) v = v > 0.f ? v : expm1f(v);
                C[crow * (size_t)ldc + n] = v;
            }
        }
    }
}

// ---------------- w_att[h,k] = sum_d a[h,d] * Wr[h*128+d, k] ----------------
__global__ __launch_bounds__(256)
void watt_kernel(const float* __restrict__ Wr, const float* __restrict__ a,
                 float* __restrict__ watt)
{
    int idx = blockIdx.x * 256 + threadIdx.x;
    if (idx >= HEADS * HIDDEN) return;
    int h = idx >> 7, k = idx & 127;
    float s = 0.f;
    #pragma unroll 4
    for (int d = 0; d < HIDDEN; ++d)
        s += a[h * HIDDEN + d] * Wr[(size_t)(h * HIDDEN + d) * HIDDEN + k];
    watt[idx] = s;
}

// ------- gather-mean + edge score + histogram: 1 wave per edge --------------
__global__ __launch_bounds__(256)
void gather_kernel(const float* __restrict__ tf, const int* __restrict__ eidx,
                   const int* __restrict__ etgt, const float* __restrict__ watt,
                   float* __restrict__ hfeat, float* __restrict__ esc,
                   int* __restrict__ cnt, int E)
{
    __shared__ float sw[HEADS * HIDDEN];
    for (int i = threadIdx.x; i < HEADS * HIDDEN; i += 256) sw[i] = watt[i];
    __syncthreads();
    int wave = threadIdx.x >> 6;
    int lane = threadIdx.x & 63;
    int e = blockIdx.x * 4 + wave;
    if (e >= E) return;
    int i0 = eidx[e * 3 + 0], i1 = eidx[e * 3 + 1], i2 = eidx[e * 3 + 2];
    const float inv3 = 1.f / 3.f;
    float v0 = (tf[(size_t)i0 * 128 + lane] + tf[(size_t)i1 * 128 + lane] +
                tf[(size_t)i2 * 128 + lane]) * inv3;
    float v1 = (tf[(size_t)i0 * 128 + 64 + lane] + tf[(size_t)i1 * 128 + 64 + lane] +
                tf[(size_t)i2 * 128 + 64 + lane]) * inv3;
    hfeat[(size_t)e * 128 + lane] = v0;
    hfeat[(size_t)e * 128 + 64 + lane] = v1;
    #pragma unroll
    for (int h = 0; h < HEADS; ++h) {
        float p = v0 * sw[h * 128 + lane] + v1 * sw[h * 128 + 64 + lane];
        #pragma unroll
        for (int o = 32; o; o >>= 1) p += __shfl_xor(p, o, 64);
        if (lane == 0) esc[(size_t)e * 4 + h] = (p >= 0.f) ? p : 0.2f * p;
    }
    if (lane == 0) atomicAdd(&cnt[etgt[e]], 1);
}

// ---------------- exclusive scan of cnt[8192] -> rowptr; zero cnt -----------
__global__ __launch_bounds__(256)
void scan_kernel(int* __restrict__ cnt, int* __restrict__ rowptr)
{
    __shared__ int part[256];
    int t = threadIdx.x;
    int vals[32];
    int s = 0;
    int base = t * 32;
    #pragma unroll
    for (int i = 0; i < 32; ++i) { vals[i] = cnt[base + i]; s += vals[i]; }
    part[t] = s;
    __syncthreads();
    for (int o = 1; o < 256; o <<= 1) {
        int v = (t >= o) ? part[t - o] : 0;
        __syncthreads();
        part[t] += v;
        __syncthreads();
    }
    int off = (t == 0) ? 0 : part[t - 1];
    #pragma unroll
    for (int i = 0; i < 32; ++i) { rowptr[base + i] = off; off += vals[i]; cnt[base + i] = 0; }
    if (t == 255) rowptr[NTGT] = off;
}

__global__ __launch_bounds__(256)
void scatter_kernel(const int* __restrict__ etgt, const int* __restrict__ rowptr,
                    int* __restrict__ cur, int* __restrict__ eids, int E)
{
    int e = blockIdx.x * 256 + threadIdx.x;
    if (e < E) {
        int t = etgt[e];
        int pos = atomicAdd(&cur[t], 1);
        eids[rowptr[t] + pos] = e;
    }
}

// ------- per-target segment softmax + weighted sum: 1 wave per target -------
__global__ __launch_bounds__(64)
void seg_kernel(const int* __restrict__ rowptr, const int* __restrict__ eids,
                const float* __restrict__ esc, const float* __restrict__ hfeat,
                float* __restrict__ gn)
{
    int t = blockIdx.x;
    int lane = threadIdx.x;
    int beg = rowptr[t], end = rowptr[t + 1];
    float mx[4] = {-INFINITY, -INFINITY, -INFINITY, -INFINITY};
    for (int i = beg + lane; i < end; i += 64) {
        int e = eids[i];
        #pragma unroll
        for (int h = 0; h < 4; ++h) mx[h] = fmaxf(mx[h], esc[(size_t)e * 4 + h]);
    }
    #pragma unroll
    for (int h = 0; h < 4; ++h) {
        #pragma unroll
        for (int o = 32; o; o >>= 1) mx[h] = fmaxf(mx[h], __shfl_xor(mx[h], o, 64));
    }
    float acc0[4] = {0, 0, 0, 0}, acc1[4] = {0, 0, 0, 0}, den[4] = {0, 0, 0, 0};
    for (int i = beg; i < end; ++i) {
        int e = eids[i];
        float f0 = hfeat[(size_t)e * 128 + lane];
        float f1 = hfeat[(size_t)e * 128 + 64 + lane];
        #pragma unroll
        for (int h = 0; h < 4; ++h) {
            float w = __expf(esc[(size_t)e * 4 + h] - mx[h]);
            den[h] += w;
            acc0[h] += w * f0;
            acc1[h] += w * f1;
        }
    }
    #pragma unroll
    for (int h = 0; h < 4; ++h) {
        float d = 1.f / (den[h] + 1e-9f);
        gn[(size_t)t * 512 + h * 128 + lane] = acc0[h] * d;
        gn[(size_t)t * 512 + h * 128 + 64 + lane] = acc1[h] * d;
    }
}

// ---------------- betas = softmax(s/8192) for a pair ------------------------
__global__ void beta_kernel(const float* __restrict__ s, float* __restrict__ beta)
{
    if (threadIdx.x == 0 && blockIdx.x == 0) {
        float b0 = s[0] * (1.f / 8192.f), b1 = s[1] * (1.f / 8192.f);
        float m = fmaxf(b0, b1);
        float e0 = __expf(b0 - m), e1 = __expf(b1 - m);
        float d = e0 + e1;
        beta[0] = e0 / d;
        beta[1] = e1 / d;
    }
}

// ---------------- out = beta0*h0 + beta1*h1 ---------------------------------
__global__ __launch_bounds__(256)
void combine_kernel(const float* __restrict__ h0, const float* __restrict__ h1,
                    const float* __restrict__ beta, float* __restrict__ out)
{
    int i = blockIdx.x * 256 + threadIdx.x;
    float b0 = beta[0], b1 = beta[1];
    float4 x = ((const float4*)h0)[i];
    float4 y = ((const float4*)h1)[i];
    float4 r;
    r.x = b0 * x.x + b1 * y.x;
    r.y = b0 * x.y + b1 * y.y;
    r.z = b0 * x.z + b1 * y.z;
    r.w = b0 * x.w + b1 * y.w;
    ((float4*)out)[i] = r;
}

extern "C" void kernel_launch(void* const* d_in, const int* in_sizes, int n_in,
                              void* d_out, int out_size, void* d_ws, size_t ws_size,
                              hipStream_t stream)
{
    const float* feat0 = (const float*)d_in[0];
    const float* feat1 = (const float*)d_in[1];
    const int* nidx0 = (const int*)d_in[2];
    const int* nidx1 = (const int*)d_in[3];
    const int* eidx[4] = {(const int*)d_in[4], (const int*)d_in[6],
                          (const int*)d_in[8], (const int*)d_in[10]};
    const int* etgt[4] = {(const int*)d_in[5], (const int*)d_in[7],
                          (const int*)d_in[9], (const int*)d_in[11]};
    const float* W0 = (const float*)d_in[12]; const float* b0 = (const float*)d_in[13];
    const float* W1 = (const float*)d_in[14]; const float* b1 = (const float*)d_in[15];
    const float* Wr[4] = {(const float*)d_in[16], (const float*)d_in[18],
                          (const float*)d_in[25], (const float*)d_in[27]};
    const float* av[4] = {(const float*)d_in[17], (const float*)d_in[19],
                          (const float*)d_in[26], (const float*)d_in[28]};
    const float* Ws[2] = {(const float*)d_in[20], (const float*)d_in[29]};
    const float* bs[2] = {(const float*)d_in[21], (const float*)d_in[30]};
    const float* vsem[2] = {(const float*)d_in[22], (const float*)d_in[31]};
    const float* Wo[2] = {(const float*)d_in[23], (const float*)d_in[32]};
    const float* bo[2] = {(const float*)d_in[24], (const float*)d_in[33]};
    float* out = (float*)d_out;

    char* p = (char*)d_ws;
    auto carve = [&](size_t bytes) { char* r = p; p += (bytes + 255) & ~(size_t)255; return r; };
    float* tf    = (float*)carve((size_t)NNODES * 128 * 4);
    float* hfeat = (float*)carve((size_t)NEDGE * 128 * 4);
    float* esc   = (float*)carve((size_t)NEDGE * 4 * 4);
    float* gn    = (float*)carve((size_t)NTGT * 512 * 4);
    float* outp1 = (float*)carve((size_t)NTGT * 512 * 4);
    float* watt  = (float*)carve(HEADS * HIDDEN * 4);
    float* ssem  = (float*)carve(4 * 4);
    float* betab = (float*)carve(4 * 4);
    int* cnt     = (int*)carve((size_t)NTGT * 4);
    int* rowptr  = (int*)carve((size_t)(NTGT + 1) * 4);
    int* eids    = (int*)carve((size_t)NEDGE * 4);

    hipMemsetAsync(tf, 0, (size_t)NNODES * 128 * 4, stream);
    hipMemsetAsync(ssem, 0, 16, stream);

    dim3 blk(256, 1, 1);

    // typed node transform (MFMA), scattered rows
    mgemm<0, 8><<<dim3(391, 1), blk, 0, stream>>>(feat0, 512, 0, W0, 512, 0, b0,
                                                  tf, 128, 0, 50000, 512,
                                                  nidx0, nullptr, nullptr);
    mgemm<0, 8><<<dim3(391, 1), blk, 0, stream>>>(feat1, 512, 0, W1, 512, 0, b1,
                                                  tf, 128, 0, 50000, 512,
                                                  nidx1, nullptr, nullptr);

    const size_t LOG_OFF[2] = {0, (size_t)NTGT * 64};
    const size_t H_OFF[2] = {(size_t)NTGT * 64 * 2,
                             (size_t)NTGT * 64 * 2 + (size_t)NTGT * 512};

    for (int nt = 0; nt < 2; ++nt) {
        float* o0 = out + H_OFF[nt];
        float* o1 = outp1;
        for (int pp = 0; pp < 2; ++pp) {
            int mp = nt * 2 + pp;
            float* ob = (pp == 0) ? o0 : o1;
            watt_kernel<<<dim3(2), blk, 0, stream>>>(Wr[mp], av[mp], watt);
            hipMemsetAsync(cnt, 0, (size_t)NTGT * 4, stream);
            gather_kernel<<<dim3(NEDGE / 4), blk, 0, stream>>>(tf, eidx[mp], etgt[mp],
                                                               watt, hfeat, esc, cnt, NEDGE);
            scan_kernel<<<dim3(1), blk, 0, stream>>>(cnt, rowptr);
            scatter_kernel<<<dim3((NEDGE + 255) / 256), blk, 0, stream>>>(etgt[mp], rowptr,
                                                                          cnt, eids, NEDGE);
            seg_kernel<<<dim3(NTGT), dim3(64), 0, stream>>>(rowptr, eids, esc, hfeat, gn);
            // out_p = elu(gn_h @ Wr_h^T) per head (grid.y = head)
            mgemm<1, 8><<<dim3(64, 4), blk, 0, stream>>>(gn, 512, 128,
                                                         Wr[mp], 128, 128 * 128, nullptr,
                                                         ob, 512, 128, NTGT, 128,
                                                         nullptr, nullptr, nullptr);
            // semantic scalar: sum tanh(out_p @ Ws^T + bs) . vs
            mgemm<2, 8><<<dim3(64, 1), blk, 0, stream>>>(ob, 512, 0, Ws[nt], 512, 0, bs[nt],
                                                         nullptr, 0, 0, NTGT, 512,
                                                         nullptr, vsem[nt], ssem + mp);
        }
        beta_kernel<<<dim3(1), dim3(64), 0, stream>>>(ssem + nt * 2, betab + nt * 2);
        combine_kernel<<<dim3(NTGT * 512 / 4 / 256), blk, 0, stream>>>(o0, o1,
                                                                       betab + nt * 2,
                                                                       out + H_OFF[nt]);
        mgemm<0, 4><<<dim3(64, 1), blk, 0, stream>>>(out + H_OFF[nt], 512, 0,
                                                     Wo[nt], 512, 0, bo[nt],
                                                     out + LOG_OFF[nt], 64, 0,
                                                     NTGT, 512,
                                                     nullptr, nullptr, nullptr);
    }
}

// Round 3
// 487.025 us; speedup vs baseline: 2.7235x; 2.2463x over previous
//
#include <hip/hip_runtime.h>
#include <hip/hip_bf16.h>
#include <math.h>

// MAGNN-style hetero-GAT forward, R3.
// - bf16 MFMA GEMMs, weights pre-converted to bf16 once (cvt kernel).
// - One merged transform dispatch (grid.z=2), merged per-metapath pipeline
//   (grid.y/z = metapath) for hist/scan/scatter/seg/EPI1/EPI2.
// - gather+seg fused into an online-softmax per-target kernel: no hfeat
//   materialization; tf rows re-gathered from L3.
// - gn stored bf16 (same rounding EPI1 applied anyway).

#define HIDDEN 128
#define HEADS 4
#define NTGT 8192
#define NEDGE 100000
#define NNODES 100000

typedef __attribute__((ext_vector_type(8))) short bf16x8;
typedef __attribute__((ext_vector_type(4))) float f32x4;

__device__ inline short b16(float f)
{
    union { __hip_bfloat16 h; short s; } u;
    u.h = __float2bfloat16(f);
    return u.s;
}

struct GArgs {   // per-blockIdx.z pointers
    const void* A[4];
    const unsigned short* B[4];
    const float* bias[4];
    float* C[4];
    const int* rowmap[4];
    const float* vs[4];
    float* sem[4];
};

// ---------------- unified MFMA GEMM: C = A(->bf16) * B^T --------------------
// A: [M][K] row-major (fp32 or bf16 per AB16); B: [N=NF*16][K] bf16 row-major.
// 4 waves/block; wave covers MI*16 rows; block covers MI*64 rows.
// EPI 0: C[row(m)][n] = acc + bias[n] (rowmap scatter optional)
// EPI 1: C = elu(acc)
// EPI 2: atomicAdd(sem, sum tanh(acc+bias[n])*vs[n])
template<int EPI, int NF, int MI, bool AB16>
__global__ __launch_bounds__(256)
void mgemm(GArgs g, int lda, int ldb, int ldc,
           int aOffY, int bOffY, int cOffY, int M, int K)
{
    __shared__ float red[4];
    const int z = blockIdx.z;
    const unsigned short* B = g.B[z] + (size_t)blockIdx.y * bOffY;
    const float* bias = g.bias[z];
    const int* rowmap = g.rowmap[z];
    float* C = g.C[z];
    if (C) C += (size_t)blockIdx.y * cOffY;
    const float* Af = nullptr;
    const unsigned short* Ah = nullptr;
    if (AB16) Ah = (const unsigned short*)g.A[z] + (size_t)blockIdx.y * aOffY;
    else      Af = (const float*)g.A[z] + (size_t)blockIdx.y * aOffY;

    const int tid = threadIdx.x;
    const int w = tid >> 6, l = tid & 63;
    const int lr = l & 15, lk = (l >> 4) * 8;
    const int m0 = blockIdx.x * (MI * 64) + w * (MI * 16);

    f32x4 acc[MI][NF];
    #pragma unroll
    for (int i = 0; i < MI; ++i)
        #pragma unroll
        for (int j = 0; j < NF; ++j)
            acc[i][j] = (f32x4){0.f, 0.f, 0.f, 0.f};

    #pragma unroll 2
    for (int k0 = 0; k0 < K; k0 += 32) {
        bf16x8 a[MI];
        #pragma unroll
        for (int i = 0; i < MI; ++i) {
            int row = min(m0 + i * 16 + lr, M - 1);
            if (AB16) {
                a[i] = *(const bf16x8*)(Ah + (size_t)row * lda + k0 + lk);
            } else {
                const float* p = Af + (size_t)row * lda + k0 + lk;
                float4 u = *(const float4*)p;
                float4 v = *(const float4*)(p + 4);
                bf16x8 r;
                r[0] = b16(u.x); r[1] = b16(u.y); r[2] = b16(u.z); r[3] = b16(u.w);
                r[4] = b16(v.x); r[5] = b16(v.y); r[6] = b16(v.z); r[7] = b16(v.w);
                a[i] = r;
            }
        }
        #pragma unroll
        for (int j = 0; j < NF; ++j) {
            bf16x8 bf = *(const bf16x8*)(B + (size_t)(j * 16 + lr) * ldb + k0 + lk);
            #pragma unroll
            for (int i = 0; i < MI; ++i)
                acc[i][j] = __builtin_amdgcn_mfma_f32_16x16x32_bf16(a[i], bf, acc[i][j], 0, 0, 0);
        }
    }

    if (EPI == 2) {
        const float* vs = g.vs[z];
        float local = 0.f;
        #pragma unroll
        for (int i = 0; i < MI; ++i) {
            int rbase = m0 + i * 16 + (l >> 4) * 4;
            #pragma unroll
            for (int r = 0; r < 4; ++r) {
                if (rbase + r >= M) continue;
                #pragma unroll
                for (int j = 0; j < NF; ++j) {
                    int n = j * 16 + lr;
                    local += tanhf(acc[i][j][r] + bias[n]) * vs[n];
                }
            }
        }
        #pragma unroll
        for (int o = 32; o; o >>= 1) local += __shfl_xor(local, o, 64);
        if (l == 0) red[w] = local;
        __syncthreads();
        if (tid == 0) atomicAdd(g.sem[z], red[0] + red[1] + red[2] + red[3]);
        return;
    }

    #pragma unroll
    for (int i = 0; i < MI; ++i) {
        int rbase = m0 + i * 16 + (l >> 4) * 4;
        #pragma unroll
        for (int r = 0; r < 4; ++r) {
            int gm = rbase + r;
            if (gm >= M) continue;
            size_t crow = rowmap ? (size_t)rowmap[gm] : (size_t)gm;
            #pragma unroll
            for (int j = 0; j < NF; ++j) {
                int n = j * 16 + lr;
                float v = acc[i][j][r];
                if (EPI == 0 && bias) v += bias[n];
                if (EPI == 1) v = v > 0.f ? v : expm1f(v);
                C[crow * (size_t)ldc + n] = v;
            }
        }
    }
}

// ---------------- convert 10 weight matrices fp32 -> bf16 -------------------
struct CvtArgs { const float* src[10]; unsigned short* dst[10]; int cnt[10]; };

__global__ __launch_bounds__(256)
void cvt_kernel(CvtArgs c)
{
    int j = blockIdx.y;
    int idx = (blockIdx.x * 256 + threadIdx.x) * 8;
    if (idx >= c.cnt[j]) return;
    const float* s = c.src[j] + idx;
    float4 u = *(const float4*)s;
    float4 v = *(const float4*)(s + 4);
    bf16x8 r;
    r[0] = b16(u.x); r[1] = b16(u.y); r[2] = b16(u.z); r[3] = b16(u.w);
    r[4] = b16(v.x); r[5] = b16(v.y); r[6] = b16(v.z); r[7] = b16(v.w);
    *(bf16x8*)(c.dst[j] + idx) = r;
}

// ---------------- watt4[mp][h][k] = sum_d a[mp][h,d] * Wr[mp][h*128+d, k] ---
struct WattArgs { const float* Wr[4]; const float* a[4]; };

__global__ __launch_bounds__(256)
void watt_kernel(WattArgs wa, float* __restrict__ watt4)
{
    int idx = blockIdx.x * 256 + threadIdx.x;   // 0..2047
    int mp = idx >> 9, rest = idx & 511, h = rest >> 7, k = rest & 127;
    const float* Wr = wa.Wr[mp];
    const float* a = wa.a[mp];
    float s = 0.f;
    #pragma unroll 4
    for (int d = 0; d < HIDDEN; ++d)
        s += a[h * HIDDEN + d] * Wr[(size_t)(h * HIDDEN + d) * HIDDEN + k];
    watt4[idx] = s;
}

// ---------------- CSR build: hist / scan / scatter (grid.y = metapath) ------
struct EArgs { const int* eidx[4]; const int* etgt[4]; };

__global__ __launch_bounds__(256)
void hist_kernel(EArgs ea, int* __restrict__ cnt4, int E)
{
    int e = blockIdx.x * 256 + threadIdx.x;
    int mp = blockIdx.y;
    if (e < E) atomicAdd(&cnt4[mp * NTGT + ea.etgt[mp][e]], 1);
}

__global__ __launch_bounds__(256)
void scan_kernel(int* __restrict__ cnt4, int* __restrict__ rowptr4)
{
    int mp = blockIdx.x;
    int* cnt = cnt4 + mp * NTGT;
    int* rowptr = rowptr4 + mp * (NTGT + 1);
    __shared__ int part[256];
    int t = threadIdx.x;
    int vals[32];
    int s = 0;
    int base = t * 32;
    #pragma unroll
    for (int i = 0; i < 32; ++i) { vals[i] = cnt[base + i]; s += vals[i]; }
    part[t] = s;
    __syncthreads();
    for (int o = 1; o < 256; o <<= 1) {
        int v = (t >= o) ? part[t - o] : 0;
        __syncthreads();
        part[t] += v;
        __syncthreads();
    }
    int off = (t == 0) ? 0 : part[t - 1];
    #pragma unroll
    for (int i = 0; i < 32; ++i) { rowptr[base + i] = off; off += vals[i]; cnt[base + i] = 0; }
    if (t == 255) rowptr[NTGT] = off;
}

__global__ __launch_bounds__(256)
void scatter_kernel(EArgs ea, const int* __restrict__ rowptr4,
                    int* __restrict__ cur4, int* __restrict__ eids4, int E)
{
    int e = blockIdx.x * 256 + threadIdx.x;
    int mp = blockIdx.y;
    if (e < E) {
        int t = ea.etgt[mp][e];
        int pos = atomicAdd(&cur4[mp * NTGT + t], 1);
        eids4[(size_t)mp * NEDGE + rowptr4[mp * (NTGT + 1) + t] + pos] = e;
    }
}

// -------- fused gather + online segment softmax + weighted sum --------------
// 1 wave per target; edges walked serially with online max-rescale.
// Writes gn directly as bf16 [mp][NTGT][512].
__global__ __launch_bounds__(256)
void seg_online(EArgs ea, const int* __restrict__ rowptr4,
                const int* __restrict__ eids4, const float* __restrict__ tf,
                const float* __restrict__ watt4, unsigned short* __restrict__ gnb)
{
    int mp = blockIdx.y;
    int w = threadIdx.x >> 6, l = threadIdx.x & 63;
    int t = blockIdx.x * 4 + w;
    const int* eidx = ea.eidx[mp];
    const int* eids = eids4 + (size_t)mp * NEDGE;
    const int* rp = rowptr4 + mp * (NTGT + 1);
    const float* wv = watt4 + mp * 512;
    float sw0[4], sw1[4];
    #pragma unroll
    for (int h = 0; h < 4; ++h) { sw0[h] = wv[h * 128 + l]; sw1[h] = wv[h * 128 + 64 + l]; }
    int beg = rp[t], end = rp[t + 1];
    float m[4] = {-INFINITY, -INFINITY, -INFINITY, -INFINITY};
    float den[4] = {0, 0, 0, 0}, a0[4] = {0, 0, 0, 0}, a1[4] = {0, 0, 0, 0};
    const float inv3 = 1.f / 3.f;
    for (int i = beg; i < end; ++i) {
        int e = eids[i];
        int i0 = eidx[e * 3 + 0], i1 = eidx[e * 3 + 1], i2 = eidx[e * 3 + 2];
        float v0 = (tf[(size_t)i0 * 128 + l] + tf[(size_t)i1 * 128 + l] +
                    tf[(size_t)i2 * 128 + l]) * inv3;
        float v1 = (tf[(size_t)i0 * 128 + 64 + l] + tf[(size_t)i1 * 128 + 64 + l] +
                    tf[(size_t)i2 * 128 + 64 + l]) * inv3;
        #pragma unroll
        for (int h = 0; h < 4; ++h) {
            float p = v0 * sw0[h] + v1 * sw1[h];
            #pragma unroll
            for (int o = 32; o; o >>= 1) p += __shfl_xor(p, o, 64);
            p = (p >= 0.f) ? p : 0.2f * p;          // leaky_relu(0.2)
            if (p > m[h]) {                          // uniform branch (p same all lanes)
                float s = __expf(m[h] - p);
                den[h] *= s; a0[h] *= s; a1[h] *= s; m[h] = p;
            }
            float wgt = __expf(p - m[h]);
            den[h] += wgt; a0[h] += wgt * v0; a1[h] += wgt * v1;
        }
    }
    unsigned short* gr = gnb + ((size_t)mp * NTGT + t) * 512;
    #pragma unroll
    for (int h = 0; h < 4; ++h) {
        float d = 1.f / (den[h] + 1e-9f);
        gr[h * 128 + l]      = (unsigned short)b16(a0[h] * d);
        gr[h * 128 + 64 + l] = (unsigned short)b16(a1[h] * d);
    }
}

// ---------------- betas = softmax over pairs (both node types) --------------
__global__ void beta_kernel(const float* __restrict__ s, float* __restrict__ beta)
{
    int nt = threadIdx.x;
    if (nt < 2 && blockIdx.x == 0) {
        float b0 = s[nt * 2] * (1.f / 8192.f), b1 = s[nt * 2 + 1] * (1.f / 8192.f);
        float mm = fmaxf(b0, b1);
        float e0 = __expf(b0 - mm), e1 = __expf(b1 - mm);
        float d = e0 + e1;
        beta[nt * 2] = e0 / d;
        beta[nt * 2 + 1] = e1 / d;
    }
}

// ---------------- out = beta0*h0 + beta1*h1 (grid.y = node type) ------------
__global__ __launch_bounds__(256)
void combine_kernel(float* __restrict__ h0base, const float* __restrict__ h1base,
                    const float* __restrict__ betab)
{
    int nt = blockIdx.y;
    size_t i = (size_t)blockIdx.x * 256 + threadIdx.x;
    float* h0 = h0base + (size_t)nt * NTGT * 512;
    const float* h1 = h1base + (size_t)nt * NTGT * 512;
    float b0 = betab[nt * 2], b1 = betab[nt * 2 + 1];
    float4 x = ((const float4*)h0)[i];
    float4 y = ((const float4*)h1)[i];
    float4 r;
    r.x = b0 * x.x + b1 * y.x;
    r.y = b0 * x.y + b1 * y.y;
    r.z = b0 * x.z + b1 * y.z;
    r.w = b0 * x.w + b1 * y.w;
    ((float4*)h0)[i] = r;
}

extern "C" void kernel_launch(void* const* d_in, const int* in_sizes, int n_in,
                              void* d_out, int out_size, void* d_ws, size_t ws_size,
                              hipStream_t stream)
{
    const float* feat0 = (const float*)d_in[0];
    const float* feat1 = (const float*)d_in[1];
    const int* nidx0 = (const int*)d_in[2];
    const int* nidx1 = (const int*)d_in[3];
    const int* eidx[4] = {(const int*)d_in[4], (const int*)d_in[6],
                          (const int*)d_in[8], (const int*)d_in[10]};
    const int* etgt[4] = {(const int*)d_in[5], (const int*)d_in[7],
                          (const int*)d_in[9], (const int*)d_in[11]};
    const float* W0 = (const float*)d_in[12]; const float* b0 = (const float*)d_in[13];
    const float* W1 = (const float*)d_in[14]; const float* b1 = (const float*)d_in[15];
    const float* Wr[4] = {(const float*)d_in[16], (const float*)d_in[18],
                          (const float*)d_in[25], (const float*)d_in[27]};
    const float* av[4] = {(const float*)d_in[17], (const float*)d_in[19],
                          (const float*)d_in[26], (const float*)d_in[28]};
    const float* Ws[2] = {(const float*)d_in[20], (const float*)d_in[29]};
    const float* bs[2] = {(const float*)d_in[21], (const float*)d_in[30]};
    const float* vsem[2] = {(const float*)d_in[22], (const float*)d_in[31]};
    const float* Wo[2] = {(const float*)d_in[23], (const float*)d_in[32]};
    const float* bo[2] = {(const float*)d_in[24], (const float*)d_in[33]};
    float* out = (float*)d_out;

    char* p = (char*)d_ws;
    auto carve = [&](size_t bytes) { char* r = p; p += (bytes + 255) & ~(size_t)255; return r; };
    float* tf            = (float*)carve((size_t)NNODES * 128 * 4);          // 51.2 MB
    unsigned short* gnb  = (unsigned short*)carve((size_t)4 * NTGT * 512 * 2); // 33.6 MB
    float* outp1         = (float*)carve((size_t)2 * NTGT * 512 * 4);        // 33.6 MB
    unsigned short* w0b  = (unsigned short*)carve(65536 * 2);
    unsigned short* w1b  = (unsigned short*)carve(65536 * 2);
    unsigned short* wrb  = (unsigned short*)carve(4 * 65536 * 2);
    unsigned short* wsb  = (unsigned short*)carve(2 * 65536 * 2);
    unsigned short* wob  = (unsigned short*)carve(2 * 32768 * 2);
    float* watt4         = (float*)carve(4 * 512 * 4);
    float* ssem          = (float*)carve(4 * 4);
    float* betab         = (float*)carve(4 * 4);
    int* cnt4            = (int*)carve((size_t)4 * NTGT * 4);
    int* rowptr4         = (int*)carve((size_t)4 * (NTGT + 1) * 4);
    int* eids4           = (int*)carve((size_t)4 * NEDGE * 4);

    hipMemsetAsync(tf, 0, (size_t)NNODES * 128 * 4, stream);
    hipMemsetAsync(ssem, 0, 16, stream);
    hipMemsetAsync(cnt4, 0, (size_t)4 * NTGT * 4, stream);

    dim3 blk(256, 1, 1);

    // weights -> bf16
    CvtArgs ca;
    ca.src[0] = W0;    ca.dst[0] = w0b;             ca.cnt[0] = 65536;
    ca.src[1] = W1;    ca.dst[1] = w1b;             ca.cnt[1] = 65536;
    for (int mp = 0; mp < 4; ++mp) {
        ca.src[2 + mp] = Wr[mp]; ca.dst[2 + mp] = wrb + mp * 65536; ca.cnt[2 + mp] = 65536;
    }
    ca.src[6] = Ws[0]; ca.dst[6] = wsb;             ca.cnt[6] = 65536;
    ca.src[7] = Ws[1]; ca.dst[7] = wsb + 65536;     ca.cnt[7] = 65536;
    ca.src[8] = Wo[0]; ca.dst[8] = wob;             ca.cnt[8] = 32768;
    ca.src[9] = Wo[1]; ca.dst[9] = wob + 32768;     ca.cnt[9] = 32768;
    cvt_kernel<<<dim3(32, 10), blk, 0, stream>>>(ca);

    WattArgs wa;
    for (int mp = 0; mp < 4; ++mp) { wa.Wr[mp] = Wr[mp]; wa.a[mp] = av[mp]; }
    watt_kernel<<<dim3(8), blk, 0, stream>>>(wa, watt4);

    // typed node transform (both types in one dispatch)
    {
        GArgs g = {};
        g.A[0] = feat0; g.A[1] = feat1;
        g.B[0] = w0b;   g.B[1] = w1b;
        g.bias[0] = b0; g.bias[1] = b1;
        g.C[0] = tf;    g.C[1] = tf;
        g.rowmap[0] = nidx0; g.rowmap[1] = nidx1;
        mgemm<0, 8, 2, false><<<dim3(391, 1, 2), blk, 0, stream>>>(
            g, 512, 512, 128, 0, 0, 0, 50000, 512);
    }

    EArgs ea;
    for (int mp = 0; mp < 4; ++mp) { ea.eidx[mp] = eidx[mp]; ea.etgt[mp] = etgt[mp]; }

    hist_kernel<<<dim3(391, 4), blk, 0, stream>>>(ea, cnt4, NEDGE);
    scan_kernel<<<dim3(4), blk, 0, stream>>>(cnt4, rowptr4);
    scatter_kernel<<<dim3(391, 4), blk, 0, stream>>>(ea, rowptr4, cnt4, eids4, NEDGE);
    seg_online<<<dim3(NTGT / 4, 4), blk, 0, stream>>>(ea, rowptr4, eids4, tf, watt4, gnb);

    const size_t LOG_OFF[2] = {0, (size_t)NTGT * 64};
    const size_t H_OFF[2] = {(size_t)NTGT * 64 * 2,
                             (size_t)NTGT * 64 * 2 + (size_t)NTGT * 512};
    float* ob[4];
    for (int mp = 0; mp < 4; ++mp) {
        int nt = mp >> 1, pp = mp & 1;
        ob[mp] = pp ? (outp1 + (size_t)nt * NTGT * 512) : (out + H_OFF[nt]);
    }

    // EPI1: ob[mp] = elu(gn[mp]_h @ Wr[mp]_h^T), grid.y = head, grid.z = mp
    {
        GArgs g = {};
        for (int mp = 0; mp < 4; ++mp) {
            g.A[mp] = gnb + (size_t)mp * NTGT * 512;
            g.B[mp] = wrb + mp * 65536;
            g.C[mp] = ob[mp];
        }
        mgemm<1, 8, 2, true><<<dim3(64, 4, 4), blk, 0, stream>>>(
            g, 512, 128, 512, 128, 16384, 128, NTGT, 128);
    }

    // EPI2: ssem[mp] += sum tanh(ob[mp] @ Ws^T + bs) . vs
    {
        GArgs g = {};
        for (int mp = 0; mp < 4; ++mp) {
            int nt = mp >> 1;
            g.A[mp] = ob[mp];
            g.B[mp] = wsb + nt * 65536;
            g.bias[mp] = bs[nt];
            g.vs[mp] = vsem[nt];
            g.sem[mp] = ssem + mp;
        }
        mgemm<2, 8, 1, false><<<dim3(128, 1, 4), blk, 0, stream>>>(
            g, 512, 512, 0, 0, 0, 0, NTGT, 512);
    }

    beta_kernel<<<dim3(1), dim3(64), 0, stream>>>(ssem, betab);
    combine_kernel<<<dim3(4096, 2), blk, 0, stream>>>(out + H_OFF[0], outp1, betab);

    // logits: out[LOG_OFF[nt]] = h[nt] @ Wo[nt]^T + bo[nt]
    {
        GArgs g = {};
        for (int nt = 0; nt < 2; ++nt) {
            g.A[nt] = out + H_OFF[nt];
            g.B[nt] = wob + nt * 32768;
            g.bias[nt] = bo[nt];
            g.C[nt] = out + LOG_OFF[nt];
        }
        mgemm<0, 4, 1, false><<<dim3(128, 1, 2), blk, 0, stream>>>(
            g, 512, 512, 64, 0, 0, 0, NTGT, 512);
    }
}

// Round 4
// 445.158 us; speedup vs baseline: 2.9796x; 1.0940x over previous
//
#include <hip/hip_runtime.h>
#include <hip/hip_bf16.h>
#include <math.h>

// MAGNN-style hetero-GAT forward, R4.
// - tf stored bf16 (halves gather volume in seg_online).
// - seg_online software-pipelined: eids two ahead, eidx/tf-rows one ahead.
// - transform GEMM MI=1 (64 rows/block) for 2x wave count (latency-bound).
// - bf16 intermediate chain: ob/h-mirror bf16 for EPI2/combine/logits reads.

#define HIDDEN 128
#define HEADS 4
#define NTGT 8192
#define NEDGE 100000
#define NNODES 100000

typedef __attribute__((ext_vector_type(8))) short bf16x8;
typedef __attribute__((ext_vector_type(4))) float f32x4;

__device__ inline short b16(float f)
{
    union { __hip_bfloat16 h; short s; } u;
    u.h = __float2bfloat16(f);
    return u.s;
}

__device__ inline float bf2f(unsigned short u)
{
    union { unsigned int i; float f; } v;
    v.i = (unsigned int)u << 16;
    return v.f;
}

struct GArgs {   // per-blockIdx.z pointers
    const void* A[4];
    const unsigned short* B[4];
    const float* bias[4];
    void* C[4];
    const int* rowmap[4];
    const float* vs[4];
    float* sem[4];
};

// ---------------- unified MFMA GEMM: C = A(->bf16) * B^T --------------------
// A: [M][K] row-major (fp32 or bf16 per AB16); B: [N=NF*16][K] bf16 row-major.
// 4 waves/block; wave covers MI*16 rows; block covers MI*64 rows.
// EPI 0: C[row(m)][n] = acc + bias[n] (rowmap scatter optional)
// EPI 1: C = elu(acc)
// EPI 2: atomicAdd(sem, sum tanh(acc+bias[n])*vs[n])
// C16: store C as bf16 (ushort) instead of fp32.
template<int EPI, int NF, int MI, bool AB16, bool C16>
__global__ __launch_bounds__(256)
void mgemm(GArgs g, int lda, int ldb, int ldc,
           int aOffY, int bOffY, int cOffY, int M, int K)
{
    __shared__ float red[4];
    const int z = blockIdx.z;
    const unsigned short* B = g.B[z] + (size_t)blockIdx.y * bOffY;
    const float* bias = g.bias[z];
    const int* rowmap = g.rowmap[z];
    float* Cf = nullptr;
    unsigned short* Ch = nullptr;
    if (g.C[z]) {
        if (C16) Ch = (unsigned short*)g.C[z] + (size_t)blockIdx.y * cOffY;
        else     Cf = (float*)g.C[z] + (size_t)blockIdx.y * cOffY;
    }
    const float* Af = nullptr;
    const unsigned short* Ah = nullptr;
    if (AB16) Ah = (const unsigned short*)g.A[z] + (size_t)blockIdx.y * aOffY;
    else      Af = (const float*)g.A[z] + (size_t)blockIdx.y * aOffY;

    const int tid = threadIdx.x;
    const int w = tid >> 6, l = tid & 63;
    const int lr = l & 15, lk = (l >> 4) * 8;
    const int m0 = blockIdx.x * (MI * 64) + w * (MI * 16);

    f32x4 acc[MI][NF];
    #pragma unroll
    for (int i = 0; i < MI; ++i)
        #pragma unroll
        for (int j = 0; j < NF; ++j)
            acc[i][j] = (f32x4){0.f, 0.f, 0.f, 0.f};

    #pragma unroll 2
    for (int k0 = 0; k0 < K; k0 += 32) {
        bf16x8 a[MI];
        #pragma unroll
        for (int i = 0; i < MI; ++i) {
            int row = min(m0 + i * 16 + lr, M - 1);
            if (AB16) {
                a[i] = *(const bf16x8*)(Ah + (size_t)row * lda + k0 + lk);
            } else {
                const float* p = Af + (size_t)row * lda + k0 + lk;
                float4 u = *(const float4*)p;
                float4 v = *(const float4*)(p + 4);
                bf16x8 r;
                r[0] = b16(u.x); r[1] = b16(u.y); r[2] = b16(u.z); r[3] = b16(u.w);
                r[4] = b16(v.x); r[5] = b16(v.y); r[6] = b16(v.z); r[7] = b16(v.w);
                a[i] = r;
            }
        }
        #pragma unroll
        for (int j = 0; j < NF; ++j) {
            bf16x8 bf = *(const bf16x8*)(B + (size_t)(j * 16 + lr) * ldb + k0 + lk);
            #pragma unroll
            for (int i = 0; i < MI; ++i)
                acc[i][j] = __builtin_amdgcn_mfma_f32_16x16x32_bf16(a[i], bf, acc[i][j], 0, 0, 0);
        }
    }

    if (EPI == 2) {
        const float* vs = g.vs[z];
        float local = 0.f;
        #pragma unroll
        for (int i = 0; i < MI; ++i) {
            int rbase = m0 + i * 16 + (l >> 4) * 4;
            #pragma unroll
            for (int r = 0; r < 4; ++r) {
                if (rbase + r >= M) continue;
                #pragma unroll
                for (int j = 0; j < NF; ++j) {
                    int n = j * 16 + lr;
                    local += tanhf(acc[i][j][r] + bias[n]) * vs[n];
                }
            }
        }
        #pragma unroll
        for (int o = 32; o; o >>= 1) local += __shfl_xor(local, o, 64);
        if (l == 0) red[w] = local;
        __syncthreads();
        if (tid == 0) atomicAdd(g.sem[z], red[0] + red[1] + red[2] + red[3]);
        return;
    }

    #pragma unroll
    for (int i = 0; i < MI; ++i) {
        int rbase = m0 + i * 16 + (l >> 4) * 4;
        #pragma unroll
        for (int r = 0; r < 4; ++r) {
            int gm = rbase + r;
            if (gm >= M) continue;
            size_t crow = rowmap ? (size_t)rowmap[gm] : (size_t)gm;
            #pragma unroll
            for (int j = 0; j < NF; ++j) {
                int n = j * 16 + lr;
                float v = acc[i][j][r];
                if (EPI == 0 && bias) v += bias[n];
                if (EPI == 1) v = v > 0.f ? v : expm1f(v);
                if (C16) Ch[crow * (size_t)ldc + n] = (unsigned short)b16(v);
                else     Cf[crow * (size_t)ldc + n] = v;
            }
        }
    }
}

// ---------------- convert 10 weight matrices fp32 -> bf16 -------------------
struct CvtArgs { const float* src[10]; unsigned short* dst[10]; int cnt[10]; };

__global__ __launch_bounds__(256)
void cvt_kernel(CvtArgs c)
{
    int j = blockIdx.y;
    int idx = (blockIdx.x * 256 + threadIdx.x) * 8;
    if (idx >= c.cnt[j]) return;
    const float* s = c.src[j] + idx;
    float4 u = *(const float4*)s;
    float4 v = *(const float4*)(s + 4);
    bf16x8 r;
    r[0] = b16(u.x); r[1] = b16(u.y); r[2] = b16(u.z); r[3] = b16(u.w);
    r[4] = b16(v.x); r[5] = b16(v.y); r[6] = b16(v.z); r[7] = b16(v.w);
    *(bf16x8*)(c.dst[j] + idx) = r;
}

// ---------------- watt4[mp][h][k] = sum_d a[mp][h,d] * Wr[mp][h*128+d, k] ---
struct WattArgs { const float* Wr[4]; const float* a[4]; };

__global__ __launch_bounds__(256)
void watt_kernel(WattArgs wa, float* __restrict__ watt4)
{
    int idx = blockIdx.x * 256 + threadIdx.x;   // 0..2047
    int mp = idx >> 9, rest = idx & 511, h = rest >> 7, k = rest & 127;
    const float* Wr = wa.Wr[mp];
    const float* a = wa.a[mp];
    float s = 0.f;
    #pragma unroll 4
    for (int d = 0; d < HIDDEN; ++d)
        s += a[h * HIDDEN + d] * Wr[(size_t)(h * HIDDEN + d) * HIDDEN + k];
    watt4[idx] = s;
}

// ---------------- CSR build: hist / scan / scatter (grid.y = metapath) ------
struct EArgs { const int* eidx[4]; const int* etgt[4]; };

__global__ __launch_bounds__(256)
void hist_kernel(EArgs ea, int* __restrict__ cnt4, int E)
{
    int e = blockIdx.x * 256 + threadIdx.x;
    int mp = blockIdx.y;
    if (e < E) atomicAdd(&cnt4[mp * NTGT + ea.etgt[mp][e]], 1);
}

__global__ __launch_bounds__(256)
void scan_kernel(int* __restrict__ cnt4, int* __restrict__ rowptr4)
{
    int mp = blockIdx.x;
    int* cnt = cnt4 + mp * NTGT;
    int* rowptr = rowptr4 + mp * (NTGT + 1);
    __shared__ int part[256];
    int t = threadIdx.x;
    int vals[32];
    int s = 0;
    int base = t * 32;
    #pragma unroll
    for (int i = 0; i < 32; ++i) { vals[i] = cnt[base + i]; s += vals[i]; }
    part[t] = s;
    __syncthreads();
    for (int o = 1; o < 256; o <<= 1) {
        int v = (t >= o) ? part[t - o] : 0;
        __syncthreads();
        part[t] += v;
        __syncthreads();
    }
    int off = (t == 0) ? 0 : part[t - 1];
    #pragma unroll
    for (int i = 0; i < 32; ++i) { rowptr[base + i] = off; off += vals[i]; cnt[base + i] = 0; }
    if (t == 255) rowptr[NTGT] = off;
}

__global__ __launch_bounds__(256)
void scatter_kernel(EArgs ea, const int* __restrict__ rowptr4,
                    int* __restrict__ cur4, int* __restrict__ eids4, int E)
{
    int e = blockIdx.x * 256 + threadIdx.x;
    int mp = blockIdx.y;
    if (e < E) {
        int t = ea.etgt[mp][e];
        int pos = atomicAdd(&cur4[mp * NTGT + t], 1);
        eids4[(size_t)mp * NEDGE + rowptr4[mp * (NTGT + 1) + t] + pos] = e;
    }
}

// -------- fused gather + online segment softmax + weighted sum --------------
// 1 wave per target; lane l holds feature pair (2l, 2l+1) as one uint (2 bf16).
// Software pipeline: eids[i+2] (linear), eidx[i+1], tf rows[i+1] issued ahead.
__global__ __launch_bounds__(256)
void seg_online(EArgs ea, const int* __restrict__ rowptr4,
                const int* __restrict__ eids4, const unsigned short* __restrict__ tfb,
                const float* __restrict__ watt4, unsigned short* __restrict__ gnb)
{
    int mp = blockIdx.y;
    int w = threadIdx.x >> 6, l = threadIdx.x & 63;
    int t = blockIdx.x * 4 + w;
    const int* eidx = ea.eidx[mp];
    const int* eids = eids4 + (size_t)mp * NEDGE;
    const int* rp = rowptr4 + mp * (NTGT + 1);
    const float* wv = watt4 + mp * 512;
    const unsigned short* tfl = tfb + 2 * l;

    float swa[4], swb[4];
    #pragma unroll
    for (int h = 0; h < 4; ++h) {
        swa[h] = wv[h * 128 + 2 * l];
        swb[h] = wv[h * 128 + 2 * l + 1];
    }

    int beg = rp[t], end = rp[t + 1];
    int n = end - beg;
    float m[4] = {-INFINITY, -INFINITY, -INFINITY, -INFINITY};
    float den[4] = {0, 0, 0, 0}, aa[4] = {0, 0, 0, 0}, ab[4] = {0, 0, 0, 0};
    const float inv3 = 1.f / 3.f;

    if (n > 0) {
        int last = end - 1;
        // prolog: edge 0 fully, edge 1 indices
        int e0 = eids[beg];
        int e1 = eids[min(beg + 1, last)];
        int a1 = eidx[e1 * 3], b1 = eidx[e1 * 3 + 1], c1 = eidx[e1 * 3 + 2];
        int a0 = eidx[e0 * 3], b0 = eidx[e0 * 3 + 1], c0 = eidx[e0 * 3 + 2];
        unsigned int x0 = *(const unsigned int*)(tfl + (size_t)a0 * 128);
        unsigned int x1 = *(const unsigned int*)(tfl + (size_t)b0 * 128);
        unsigned int x2 = *(const unsigned int*)(tfl + (size_t)c0 * 128);
        for (int i = 0; i < n; ++i) {
            // issue next-edge row loads + next-next indices
            unsigned int y0 = *(const unsigned int*)(tfl + (size_t)a1 * 128);
            unsigned int y1 = *(const unsigned int*)(tfl + (size_t)b1 * 128);
            unsigned int y2 = *(const unsigned int*)(tfl + (size_t)c1 * 128);
            int e2 = eids[min(beg + i + 2, last)];
            int a2 = eidx[e2 * 3], b2 = eidx[e2 * 3 + 1], c2 = eidx[e2 * 3 + 2];
            // compute on current rows
            float fa = (bf2f((unsigned short)x0) + bf2f((unsigned short)x1) +
                        bf2f((unsigned short)x2)) * inv3;
            float fb = (bf2f((unsigned short)(x0 >> 16)) + bf2f((unsigned short)(x1 >> 16)) +
                        bf2f((unsigned short)(x2 >> 16))) * inv3;
            float p[4];
            #pragma unroll
            for (int h = 0; h < 4; ++h) p[h] = fa * swa[h] + fb * swb[h];
            #pragma unroll
            for (int h = 0; h < 4; ++h)
                #pragma unroll
                for (int o = 32; o; o >>= 1) p[h] += __shfl_xor(p[h], o, 64);
            #pragma unroll
            for (int h = 0; h < 4; ++h) {
                float pv = p[h];
                pv = (pv >= 0.f) ? pv : 0.2f * pv;      // leaky_relu(0.2)
                if (pv > m[h]) {                         // wave-uniform branch
                    float s = __expf(m[h] - pv);
                    den[h] *= s; aa[h] *= s; ab[h] *= s; m[h] = pv;
                }
                float wgt = __expf(pv - m[h]);
                den[h] += wgt; aa[h] += wgt * fa; ab[h] += wgt * fb;
            }
            // rotate pipeline
            x0 = y0; x1 = y1; x2 = y2;
            a1 = a2; b1 = b2; c1 = c2;
        }
    }

    unsigned short* gr = gnb + ((size_t)mp * NTGT + t) * 512;
    #pragma unroll
    for (int h = 0; h < 4; ++h) {
        float d = 1.f / (den[h] + 1e-9f);
        unsigned int lo = (unsigned int)(unsigned short)b16(aa[h] * d);
        unsigned int hi = (unsigned int)(unsigned short)b16(ab[h] * d);
        *(unsigned int*)(gr + h * 128 + 2 * l) = lo | (hi << 16);
    }
}

// ---------------- betas = softmax over pairs (both node types) --------------
__global__ void beta_kernel(const float* __restrict__ s, float* __restrict__ beta)
{
    int nt = threadIdx.x;
    if (nt < 2 && blockIdx.x == 0) {
        float b0 = s[nt * 2] * (1.f / 8192.f), b1 = s[nt * 2 + 1] * (1.f / 8192.f);
        float mm = fmaxf(b0, b1);
        float e0 = __expf(b0 - mm), e1 = __expf(b1 - mm);
        float d = e0 + e1;
        beta[nt * 2] = e0 / d;
        beta[nt * 2 + 1] = e1 / d;
    }
}

// -------- h = beta0*ob0 + beta1*ob1 (bf16 in, fp32 out + bf16 mirror) -------
__global__ __launch_bounds__(256)
void combine_kernel(const unsigned short* __restrict__ obb,
                    const float* __restrict__ betab,
                    float* __restrict__ hout, unsigned short* __restrict__ hb)
{
    int nt = blockIdx.y;
    size_t i4 = ((size_t)blockIdx.x * 256 + threadIdx.x) * 4;
    const unsigned short* o0 = obb + (size_t)(2 * nt) * NTGT * 512 + i4;
    const unsigned short* o1 = obb + (size_t)(2 * nt + 1) * NTGT * 512 + i4;
    float b0 = betab[nt * 2], b1 = betab[nt * 2 + 1];
    uint2 xa = *(const uint2*)o0;
    uint2 xb = *(const uint2*)o1;
    float4 r;
    r.x = b0 * bf2f((unsigned short)xa.x)         + b1 * bf2f((unsigned short)xb.x);
    r.y = b0 * bf2f((unsigned short)(xa.x >> 16)) + b1 * bf2f((unsigned short)(xb.x >> 16));
    r.z = b0 * bf2f((unsigned short)xa.y)         + b1 * bf2f((unsigned short)xb.y);
    r.w = b0 * bf2f((unsigned short)(xa.y >> 16)) + b1 * bf2f((unsigned short)(xb.y >> 16));
    *(float4*)(hout + (size_t)nt * NTGT * 512 + i4) = r;
    unsigned int lo = (unsigned int)(unsigned short)b16(r.x) |
                      ((unsigned int)(unsigned short)b16(r.y) << 16);
    unsigned int hi = (unsigned int)(unsigned short)b16(r.z) |
                      ((unsigned int)(unsigned short)b16(r.w) << 16);
    *(uint2*)(hb + (size_t)nt * NTGT * 512 + i4) = make_uint2(lo, hi);
}

extern "C" void kernel_launch(void* const* d_in, const int* in_sizes, int n_in,
                              void* d_out, int out_size, void* d_ws, size_t ws_size,
                              hipStream_t stream)
{
    const float* feat0 = (const float*)d_in[0];
    const float* feat1 = (const float*)d_in[1];
    const int* nidx0 = (const int*)d_in[2];
    const int* nidx1 = (const int*)d_in[3];
    const int* eidx[4] = {(const int*)d_in[4], (const int*)d_in[6],
                          (const int*)d_in[8], (const int*)d_in[10]};
    const int* etgt[4] = {(const int*)d_in[5], (const int*)d_in[7],
                          (const int*)d_in[9], (const int*)d_in[11]};
    const float* W0 = (const float*)d_in[12]; const float* b0 = (const float*)d_in[13];
    const float* W1 = (const float*)d_in[14]; const float* b1 = (const float*)d_in[15];
    const float* Wr[4] = {(const float*)d_in[16], (const float*)d_in[18],
                          (const float*)d_in[25], (const float*)d_in[27]};
    const float* av[4] = {(const float*)d_in[17], (const float*)d_in[19],
                          (const float*)d_in[26], (const float*)d_in[28]};
    const float* Ws[2] = {(const float*)d_in[20], (const float*)d_in[29]};
    const float* bs[2] = {(const float*)d_in[21], (const float*)d_in[30]};
    const float* vsem[2] = {(const float*)d_in[22], (const float*)d_in[31]};
    const float* Wo[2] = {(const float*)d_in[23], (const float*)d_in[32]};
    const float* bo[2] = {(const float*)d_in[24], (const float*)d_in[33]};
    float* out = (float*)d_out;

    char* p = (char*)d_ws;
    auto carve = [&](size_t bytes) { char* r = p; p += (bytes + 255) & ~(size_t)255; return r; };
    unsigned short* tfb = (unsigned short*)carve((size_t)NNODES * 128 * 2);     // 25.6 MB
    unsigned short* gnb = (unsigned short*)carve((size_t)4 * NTGT * 512 * 2);   // 33.6 MB
    unsigned short* obb = (unsigned short*)carve((size_t)4 * NTGT * 512 * 2);   // 33.6 MB
    unsigned short* hb  = (unsigned short*)carve((size_t)2 * NTGT * 512 * 2);   // 16.8 MB
    unsigned short* w0b = (unsigned short*)carve(65536 * 2);
    unsigned short* w1b = (unsigned short*)carve(65536 * 2);
    unsigned short* wrb = (unsigned short*)carve(4 * 65536 * 2);
    unsigned short* wsb = (unsigned short*)carve(2 * 65536 * 2);
    unsigned short* wob = (unsigned short*)carve(2 * 32768 * 2);
    float* watt4        = (float*)carve(4 * 512 * 4);
    float* ssem         = (float*)carve(4 * 4);
    float* betab        = (float*)carve(4 * 4);
    int* cnt4           = (int*)carve((size_t)4 * NTGT * 4);
    int* rowptr4        = (int*)carve((size_t)4 * (NTGT + 1) * 4);
    int* eids4          = (int*)carve((size_t)4 * NEDGE * 4);

    hipMemsetAsync(tfb, 0, (size_t)NNODES * 128 * 2, stream);
    hipMemsetAsync(ssem, 0, 16, stream);
    hipMemsetAsync(cnt4, 0, (size_t)4 * NTGT * 4, stream);

    dim3 blk(256, 1, 1);

    // weights -> bf16
    CvtArgs ca;
    ca.src[0] = W0;    ca.dst[0] = w0b;             ca.cnt[0] = 65536;
    ca.src[1] = W1;    ca.dst[1] = w1b;             ca.cnt[1] = 65536;
    for (int mp = 0; mp < 4; ++mp) {
        ca.src[2 + mp] = Wr[mp]; ca.dst[2 + mp] = wrb + mp * 65536; ca.cnt[2 + mp] = 65536;
    }
    ca.src[6] = Ws[0]; ca.dst[6] = wsb;             ca.cnt[6] = 65536;
    ca.src[7] = Ws[1]; ca.dst[7] = wsb + 65536;     ca.cnt[7] = 65536;
    ca.src[8] = Wo[0]; ca.dst[8] = wob;             ca.cnt[8] = 32768;
    ca.src[9] = Wo[1]; ca.dst[9] = wob + 32768;     ca.cnt[9] = 32768;
    cvt_kernel<<<dim3(32, 10), blk, 0, stream>>>(ca);

    WattArgs wa;
    for (int mp = 0; mp < 4; ++mp) { wa.Wr[mp] = Wr[mp]; wa.a[mp] = av[mp]; }
    watt_kernel<<<dim3(8), blk, 0, stream>>>(wa, watt4);

    // typed node transform -> tfb (bf16), both types in one dispatch
    {
        GArgs g = {};
        g.A[0] = feat0; g.A[1] = feat1;
        g.B[0] = w0b;   g.B[1] = w1b;
        g.bias[0] = b0; g.bias[1] = b1;
        g.C[0] = tfb;   g.C[1] = tfb;
        g.rowmap[0] = nidx0; g.rowmap[1] = nidx1;
        mgemm<0, 8, 1, false, true><<<dim3(782, 1, 2), blk, 0, stream>>>(
            g, 512, 512, 128, 0, 0, 0, 50000, 512);
    }

    EArgs ea;
    for (int mp = 0; mp < 4; ++mp) { ea.eidx[mp] = eidx[mp]; ea.etgt[mp] = etgt[mp]; }

    hist_kernel<<<dim3(391, 4), blk, 0, stream>>>(ea, cnt4, NEDGE);
    scan_kernel<<<dim3(4), blk, 0, stream>>>(cnt4, rowptr4);
    scatter_kernel<<<dim3(391, 4), blk, 0, stream>>>(ea, rowptr4, cnt4, eids4, NEDGE);
    seg_online<<<dim3(NTGT / 4, 4), blk, 0, stream>>>(ea, rowptr4, eids4, tfb, watt4, gnb);

    const size_t LOG_OFF[2] = {0, (size_t)NTGT * 64};
    float* hout = out + (size_t)NTGT * 128;   // h regions: [2][NTGT][512] contiguous

    // EPI1: obb[mp] = elu(gn[mp]_h @ Wr[mp]_h^T) bf16, grid.y = head, grid.z = mp
    {
        GArgs g = {};
        for (int mp = 0; mp < 4; ++mp) {
            g.A[mp] = gnb + (size_t)mp * NTGT * 512;
            g.B[mp] = wrb + mp * 65536;
            g.C[mp] = obb + (size_t)mp * NTGT * 512;
        }
        mgemm<1, 8, 2, true, true><<<dim3(64, 4, 4), blk, 0, stream>>>(
            g, 512, 128, 512, 128, 16384, 128, NTGT, 128);
    }

    // EPI2: ssem[mp] += sum tanh(obb[mp] @ Ws^T + bs) . vs
    {
        GArgs g = {};
        for (int mp = 0; mp < 4; ++mp) {
            int nt = mp >> 1;
            g.A[mp] = obb + (size_t)mp * NTGT * 512;
            g.B[mp] = wsb + nt * 65536;
            g.bias[mp] = bs[nt];
            g.vs[mp] = vsem[nt];
            g.sem[mp] = ssem + mp;
        }
        mgemm<2, 8, 1, true, false><<<dim3(128, 1, 4), blk, 0, stream>>>(
            g, 512, 512, 0, 0, 0, 0, NTGT, 512);
    }

    beta_kernel<<<dim3(1), dim3(64), 0, stream>>>(ssem, betab);
    combine_kernel<<<dim3(NTGT * 512 / 4 / 256, 2), blk, 0, stream>>>(obb, betab, hout, hb);

    // logits: out[LOG_OFF[nt]] = h[nt] @ Wo[nt]^T + bo[nt]
    {
        GArgs g = {};
        for (int nt = 0; nt < 2; ++nt) {
            g.A[nt] = hb + (size_t)nt * NTGT * 512;
            g.B[nt] = wob + nt * 32768;
            g.bias[nt] = bo[nt];
            g.C[nt] = out + LOG_OFF[nt];
        }
        mgemm<0, 4, 1, true, false><<<dim3(128, 1, 2), blk, 0, stream>>>(
            g, 512, 512, 64, 0, 0, 0, NTGT, 512);
    }
}

// Round 5
// 344.215 us; speedup vs baseline: 3.8534x; 1.2933x over previous
//
#include <hip/hip_runtime.h>
#include <hip/hip_bf16.h>
#include <math.h>

// MAGNN-style hetero-GAT forward, R5.
// - mgemm: explicit double-buffered register prefetch (named stages, unroll-2).
// - B matrices pre-packed to MFMA frag-major layout (1KB contiguous per frag).
// - transform MI=2 (12 waves/CU + depth-1 prefetch ILP).
// - seg_online: depth-2 row prefetch (rows i+1, i+2 in flight, indices 3 ahead).

#define HIDDEN 128
#define HEADS 4
#define NTGT 8192
#define NEDGE 100000
#define NNODES 100000

typedef __attribute__((ext_vector_type(8))) short bf16x8;
typedef __attribute__((ext_vector_type(4))) float f32x4;

__device__ inline short b16(float f)
{
    union { __hip_bfloat16 h; short s; } u;
    u.h = __float2bfloat16(f);
    return u.s;
}

__device__ inline float bf2f(unsigned short u)
{
    union { unsigned int i; float f; } v;
    v.i = (unsigned int)u << 16;
    return v.f;
}

struct GArgs {   // per-blockIdx.z pointers
    const void* A[4];
    const unsigned short* B[4];   // packed frag-major
    const float* bias[4];
    void* C[4];
    const int* rowmap[4];
    const float* vs[4];
    float* sem[4];
};

// ---------------- unified MFMA GEMM: C = A(->bf16) * Bpacked ----------------
// A: [M][K] row-major (fp32 or bf16 per AB16).
// B packed frag-major: frag (k0/32, j) at ((k0/32)*NF + j)*512 + lane*8.
// 4 waves/block; wave covers MI*16 rows; block covers MI*64 rows. K % 64 == 0.
// EPI 0: C[row(m)][n] = acc + bias[n] (rowmap scatter optional)
// EPI 1: C = elu(acc)
// EPI 2: atomicAdd(sem, sum tanh(acc+bias[n])*vs[n])
// C16: store C as bf16.
template<int EPI, int NF, int MI, bool AB16, bool C16>
__global__ __launch_bounds__(256)
void mgemm(GArgs g, int lda, int ldc,
           int aOffY, int bOffY, int cOffY, int M, int K)
{
    __shared__ float red[4];
    const int z = blockIdx.z;
    const unsigned short* Bp = g.B[z] + (size_t)blockIdx.y * bOffY;
    const float* bias = g.bias[z];
    const int* rowmap = g.rowmap[z];
    float* Cf = nullptr;
    unsigned short* Ch = nullptr;
    if (g.C[z]) {
        if (C16) Ch = (unsigned short*)g.C[z] + (size_t)blockIdx.y * cOffY;
        else     Cf = (float*)g.C[z] + (size_t)blockIdx.y * cOffY;
    }
    const float* Af = nullptr;
    const unsigned short* Ah = nullptr;
    if (AB16) Ah = (const unsigned short*)g.A[z] + (size_t)blockIdx.y * aOffY;
    else      Af = (const float*)g.A[z] + (size_t)blockIdx.y * aOffY;

    const int tid = threadIdx.x;
    const int w = tid >> 6, l = tid & 63;
    const int lr = l & 15, lk = (l >> 4) * 8;
    const int m0 = blockIdx.x * (MI * 64) + w * (MI * 16);

    f32x4 acc[MI][NF];
    #pragma unroll
    for (int i = 0; i < MI; ++i)
        #pragma unroll
        for (int j = 0; j < NF; ++j)
            acc[i][j] = (f32x4){0.f, 0.f, 0.f, 0.f};

    // two named stage buffers (static indexing -> registers)
    float4 af0[MI][2], af1[MI][2];
    bf16x8 ah0[MI], ah1[MI];
    bf16x8 bb0[NF], bb1[NF];

    auto LD = [&](int k0, float4 (&af)[MI][2], bf16x8 (&ah)[MI], bf16x8 (&bb)[NF]) {
        #pragma unroll
        for (int i = 0; i < MI; ++i) {
            int row = min(m0 + i * 16 + lr, M - 1);
            if (AB16) {
                ah[i] = *(const bf16x8*)(Ah + (size_t)row * lda + k0 + lk);
            } else {
                const float* p = Af + (size_t)row * lda + k0 + lk;
                af[i][0] = *(const float4*)p;
                af[i][1] = *(const float4*)(p + 4);
            }
        }
        #pragma unroll
        for (int j = 0; j < NF; ++j)
            bb[j] = *(const bf16x8*)(Bp + ((size_t)((k0 >> 5) * NF + j) * 64 + l) * 8);
    };

    auto CMP = [&](float4 (&af)[MI][2], bf16x8 (&ah)[MI], bf16x8 (&bb)[NF]) {
        bf16x8 a[MI];
        #pragma unroll
        for (int i = 0; i < MI; ++i) {
            if (AB16) {
                a[i] = ah[i];
            } else {
                bf16x8 r;
                r[0] = b16(af[i][0].x); r[1] = b16(af[i][0].y);
                r[2] = b16(af[i][0].z); r[3] = b16(af[i][0].w);
                r[4] = b16(af[i][1].x); r[5] = b16(af[i][1].y);
                r[6] = b16(af[i][1].z); r[7] = b16(af[i][1].w);
                a[i] = r;
            }
        }
        #pragma unroll
        for (int j = 0; j < NF; ++j)
            #pragma unroll
            for (int i = 0; i < MI; ++i)
                acc[i][j] = __builtin_amdgcn_mfma_f32_16x16x32_bf16(a[i], bb[j], acc[i][j], 0, 0, 0);
    };

    LD(0, af0, ah0, bb0);
    for (int k0 = 0; k0 < K; k0 += 64) {
        LD(k0 + 32, af1, ah1, bb1);
        CMP(af0, ah0, bb0);
        if (k0 + 64 < K) LD(k0 + 64, af0, ah0, bb0);
        CMP(af1, ah1, bb1);
    }

    if (EPI == 2) {
        const float* vs = g.vs[z];
        float local = 0.f;
        #pragma unroll
        for (int i = 0; i < MI; ++i) {
            int rbase = m0 + i * 16 + (l >> 4) * 4;
            #pragma unroll
            for (int r = 0; r < 4; ++r) {
                if (rbase + r >= M) continue;
                #pragma unroll
                for (int j = 0; j < NF; ++j) {
                    int n = j * 16 + lr;
                    local += tanhf(acc[i][j][r] + bias[n]) * vs[n];
                }
            }
        }
        #pragma unroll
        for (int o = 32; o; o >>= 1) local += __shfl_xor(local, o, 64);
        if (l == 0) red[w] = local;
        __syncthreads();
        if (tid == 0) atomicAdd(g.sem[z], red[0] + red[1] + red[2] + red[3]);
        return;
    }

    #pragma unroll
    for (int i = 0; i < MI; ++i) {
        int rbase = m0 + i * 16 + (l >> 4) * 4;
        #pragma unroll
        for (int r = 0; r < 4; ++r) {
            int gm = rbase + r;
            if (gm >= M) continue;
            size_t crow = rowmap ? (size_t)rowmap[gm] : (size_t)gm;
            #pragma unroll
            for (int j = 0; j < NF; ++j) {
                int n = j * 16 + lr;
                float v = acc[i][j][r];
                if (EPI == 0 && bias) v += bias[n];
                if (EPI == 1) v = v > 0.f ? v : expm1f(v);
                if (C16) Ch[crow * (size_t)ldc + n] = (unsigned short)b16(v);
                else     Cf[crow * (size_t)ldc + n] = v;
            }
        }
    }
}

// ------- pack fp32 weight matrices -> bf16 MFMA frag-major layout -----------
// chunk c: src [n16*16][k32*32] fp32 (leading dim ld); dst elem (k0,j,lane):
// row = j*16+(l&15), col = k0*32+(l>>4)*8; dst offset = idx*8 (idx linear).
struct PackArgs {
    const float* src[22];
    unsigned short* dst[22];
    int n16[22], k32[22], ld[22];
};

__global__ __launch_bounds__(256)
void pack_kernel(PackArgs pa)
{
    int c = blockIdx.y;
    int idx = blockIdx.x * 256 + threadIdx.x;
    int tot = pa.n16[c] * pa.k32[c] * 64;
    if (idx >= tot) return;
    int l = idx & 63;
    int rest = idx >> 6;
    int j = rest % pa.n16[c];
    int k0 = rest / pa.n16[c];
    int row = j * 16 + (l & 15);
    int col = k0 * 32 + (l >> 4) * 8;
    const float* s = pa.src[c] + (size_t)row * pa.ld[c] + col;
    float4 u = *(const float4*)s;
    float4 v = *(const float4*)(s + 4);
    bf16x8 r;
    r[0] = b16(u.x); r[1] = b16(u.y); r[2] = b16(u.z); r[3] = b16(u.w);
    r[4] = b16(v.x); r[5] = b16(v.y); r[6] = b16(v.z); r[7] = b16(v.w);
    *(bf16x8*)(pa.dst[c] + (size_t)idx * 8) = r;
}

// ---------------- watt4[mp][h][k] = sum_d a[mp][h,d] * Wr[mp][h*128+d, k] ---
struct WattArgs { const float* Wr[4]; const float* a[4]; };

__global__ __launch_bounds__(256)
void watt_kernel(WattArgs wa, float* __restrict__ watt4)
{
    int idx = blockIdx.x * 256 + threadIdx.x;   // 0..2047
    int mp = idx >> 9, rest = idx & 511, h = rest >> 7, k = rest & 127;
    const float* Wr = wa.Wr[mp];
    const float* a = wa.a[mp];
    float s = 0.f;
    #pragma unroll 4
    for (int d = 0; d < HIDDEN; ++d)
        s += a[h * HIDDEN + d] * Wr[(size_t)(h * HIDDEN + d) * HIDDEN + k];
    watt4[idx] = s;
}

// ---------------- CSR build: hist / scan / scatter (grid.y = metapath) ------
struct EArgs { const int* eidx[4]; const int* etgt[4]; };

__global__ __launch_bounds__(256)
void hist_kernel(EArgs ea, int* __restrict__ cnt4, int E)
{
    int e = blockIdx.x * 256 + threadIdx.x;
    int mp = blockIdx.y;
    if (e < E) atomicAdd(&cnt4[mp * NTGT + ea.etgt[mp][e]], 1);
}

__global__ __launch_bounds__(256)
void scan_kernel(int* __restrict__ cnt4, int* __restrict__ rowptr4)
{
    int mp = blockIdx.x;
    int* cnt = cnt4 + mp * NTGT;
    int* rowptr = rowptr4 + mp * (NTGT + 1);
    __shared__ int part[256];
    int t = threadIdx.x;
    int vals[32];
    int s = 0;
    int base = t * 32;
    #pragma unroll
    for (int i = 0; i < 32; ++i) { vals[i] = cnt[base + i]; s += vals[i]; }
    part[t] = s;
    __syncthreads();
    for (int o = 1; o < 256; o <<= 1) {
        int v = (t >= o) ? part[t - o] : 0;
        __syncthreads();
        part[t] += v;
        __syncthreads();
    }
    int off = (t == 0) ? 0 : part[t - 1];
    #pragma unroll
    for (int i = 0; i < 32; ++i) { rowptr[base + i] = off; off += vals[i]; cnt[base + i] = 0; }
    if (t == 255) rowptr[NTGT] = off;
}

__global__ __launch_bounds__(256)
void scatter_kernel(EArgs ea, const int* __restrict__ rowptr4,
                    int* __restrict__ cur4, int* __restrict__ eids4, int E)
{
    int e = blockIdx.x * 256 + threadIdx.x;
    int mp = blockIdx.y;
    if (e < E) {
        int t = ea.etgt[mp][e];
        int pos = atomicAdd(&cur4[mp * NTGT + t], 1);
        eids4[(size_t)mp * NEDGE + rowptr4[mp * (NTGT + 1) + t] + pos] = e;
    }
}

// -------- fused gather + online segment softmax + weighted sum --------------
// 1 wave per target; lane l holds feature pair (2l, 2l+1) as one uint (2 bf16).
// Depth-2 pipeline: rows for edges i+1 and i+2 in flight, indices 3 ahead.
__global__ __launch_bounds__(256)
void seg_online(EArgs ea, const int* __restrict__ rowptr4,
                const int* __restrict__ eids4, const unsigned short* __restrict__ tfb,
                const float* __restrict__ watt4, unsigned short* __restrict__ gnb)
{
    int mp = blockIdx.y;
    int w = threadIdx.x >> 6, l = threadIdx.x & 63;
    int t = blockIdx.x * 4 + w;
    const int* eidx = ea.eidx[mp];
    const int* eids = eids4 + (size_t)mp * NEDGE;
    const int* rp = rowptr4 + mp * (NTGT + 1);
    const float* wv = watt4 + mp * 512;
    const unsigned short* tfl = tfb + 2 * l;

    float swa[4], swb[4];
    #pragma unroll
    for (int h = 0; h < 4; ++h) {
        swa[h] = wv[h * 128 + 2 * l];
        swb[h] = wv[h * 128 + 2 * l + 1];
    }

    int beg = rp[t], end = rp[t + 1];
    int n = end - beg;
    float m[4] = {-INFINITY, -INFINITY, -INFINITY, -INFINITY};
    float den[4] = {0, 0, 0, 0}, aa[4] = {0, 0, 0, 0}, ab[4] = {0, 0, 0, 0};
    const float inv3 = 1.f / 3.f;

    if (n > 0) {
        int last = end - 1;
        int e0 = eids[beg];
        int e1 = eids[min(beg + 1, last)];
        int e2 = eids[min(beg + 2, last)];
        int A0 = eidx[e0 * 3], B0 = eidx[e0 * 3 + 1], C0 = eidx[e0 * 3 + 2];
        int A1 = eidx[e1 * 3], B1 = eidx[e1 * 3 + 1], C1 = eidx[e1 * 3 + 2];
        int A2 = eidx[e2 * 3], B2 = eidx[e2 * 3 + 1], C2 = eidx[e2 * 3 + 2];
        unsigned int x0 = *(const unsigned int*)(tfl + (size_t)A0 * 128);
        unsigned int x1 = *(const unsigned int*)(tfl + (size_t)B0 * 128);
        unsigned int x2 = *(const unsigned int*)(tfl + (size_t)C0 * 128);
        unsigned int y0 = *(const unsigned int*)(tfl + (size_t)A1 * 128);
        unsigned int y1 = *(const unsigned int*)(tfl + (size_t)B1 * 128);
        unsigned int y2 = *(const unsigned int*)(tfl + (size_t)C1 * 128);
        for (int i = 0; i < n; ++i) {
            // prefetch rows for edge i+2 and indices for edge i+3
            unsigned int z0 = *(const unsigned int*)(tfl + (size_t)A2 * 128);
            unsigned int z1 = *(const unsigned int*)(tfl + (size_t)B2 * 128);
            unsigned int z2 = *(const unsigned int*)(tfl + (size_t)C2 * 128);
            int e3 = eids[min(beg + i + 3, last)];
            int A3 = eidx[e3 * 3], B3 = eidx[e3 * 3 + 1], C3 = eidx[e3 * 3 + 2];
            // compute on edge i (rows x*)
            float fa = (bf2f((unsigned short)x0) + bf2f((unsigned short)x1) +
                        bf2f((unsigned short)x2)) * inv3;
            float fb = (bf2f((unsigned short)(x0 >> 16)) + bf2f((unsigned short)(x1 >> 16)) +
                        bf2f((unsigned short)(x2 >> 16))) * inv3;
            float p[4];
            #pragma unroll
            for (int h = 0; h < 4; ++h) p[h] = fa * swa[h] + fb * swb[h];
            #pragma unroll
            for (int h = 0; h < 4; ++h)
                #pragma unroll
                for (int o = 32; o; o >>= 1) p[h] += __shfl_xor(p[h], o, 64);
            #pragma unroll
            for (int h = 0; h < 4; ++h) {
                float pv = p[h];
                pv = (pv >= 0.f) ? pv : 0.2f * pv;      // leaky_relu(0.2)
                if (pv > m[h]) {                         // wave-uniform branch
                    float s = __expf(m[h] - pv);
                    den[h] *= s; aa[h] *= s; ab[h] *= s; m[h] = pv;
                }
                float wgt = __expf(pv - m[h]);
                den[h] += wgt; aa[h] += wgt * fa; ab[h] += wgt * fb;
            }
            // rotate pipeline
            x0 = y0; x1 = y1; x2 = y2;
            y0 = z0; y1 = z1; y2 = z2;
            A2 = A3; B2 = B3; C2 = C3;
        }
    }

    unsigned short* gr = gnb + ((size_t)mp * NTGT + t) * 512;
    #pragma unroll
    for (int h = 0; h < 4; ++h) {
        float d = 1.f / (den[h] + 1e-9f);
        unsigned int lo = (unsigned int)(unsigned short)b16(aa[h] * d);
        unsigned int hi = (unsigned int)(unsigned short)b16(ab[h] * d);
        *(unsigned int*)(gr + h * 128 + 2 * l) = lo | (hi << 16);
    }
}

// ---------------- betas = softmax over pairs (both node types) --------------
__global__ void beta_kernel(const float* __restrict__ s, float* __restrict__ beta)
{
    int nt = threadIdx.x;
    if (nt < 2 && blockIdx.x == 0) {
        float b0 = s[nt * 2] * (1.f / 8192.f), b1 = s[nt * 2 + 1] * (1.f / 8192.f);
        float mm = fmaxf(b0, b1);
        float e0 = __expf(b0 - mm), e1 = __expf(b1 - mm);
        float d = e0 + e1;
        beta[nt * 2] = e0 / d;
        beta[nt * 2 + 1] = e1 / d;
    }
}

// -------- h = beta0*ob0 + beta1*ob1 (bf16 in, fp32 out + bf16 mirror) -------
__global__ __launch_bounds__(256)
void combine_kernel(const unsigned short* __restrict__ obb,
                    const float* __restrict__ betab,
                    float* __restrict__ hout, unsigned short* __restrict__ hb)
{
    int nt = blockIdx.y;
    size_t i4 = ((size_t)blockIdx.x * 256 + threadIdx.x) * 4;
    const unsigned short* o0 = obb + (size_t)(2 * nt) * NTGT * 512 + i4;
    const unsigned short* o1 = obb + (size_t)(2 * nt + 1) * NTGT * 512 + i4;
    float b0 = betab[nt * 2], b1 = betab[nt * 2 + 1];
    uint2 xa = *(const uint2*)o0;
    uint2 xb = *(const uint2*)o1;
    float4 r;
    r.x = b0 * bf2f((unsigned short)xa.x)         + b1 * bf2f((unsigned short)xb.x);
    r.y = b0 * bf2f((unsigned short)(xa.x >> 16)) + b1 * bf2f((unsigned short)(xb.x >> 16));
    r.z = b0 * bf2f((unsigned short)xa.y)         + b1 * bf2f((unsigned short)xb.y);
    r.w = b0 * bf2f((unsigned short)(xa.y >> 16)) + b1 * bf2f((unsigned short)(xb.y >> 16));
    *(float4*)(hout + (size_t)nt * NTGT * 512 + i4) = r;
    unsigned int lo = (unsigned int)(unsigned short)b16(r.x) |
                      ((unsigned int)(unsigned short)b16(r.y) << 16);
    unsigned int hi = (unsigned int)(unsigned short)b16(r.z) |
                      ((unsigned int)(unsigned short)b16(r.w) << 16);
    *(uint2*)(hb + (size_t)nt * NTGT * 512 + i4) = make_uint2(lo, hi);
}

extern "C" void kernel_launch(void* const* d_in, const int* in_sizes, int n_in,
                              void* d_out, int out_size, void* d_ws, size_t ws_size,
                              hipStream_t stream)
{
    const float* feat0 = (const float*)d_in[0];
    const float* feat1 = (const float*)d_in[1];
    const int* nidx0 = (const int*)d_in[2];
    const int* nidx1 = (const int*)d_in[3];
    const int* eidx[4] = {(const int*)d_in[4], (const int*)d_in[6],
                          (const int*)d_in[8], (const int*)d_in[10]};
    const int* etgt[4] = {(const int*)d_in[5], (const int*)d_in[7],
                          (const int*)d_in[9], (const int*)d_in[11]};
    const float* W0 = (const float*)d_in[12]; const float* b0 = (const float*)d_in[13];
    const float* W1 = (const float*)d_in[14]; const float* b1 = (const float*)d_in[15];
    const float* Wr[4] = {(const float*)d_in[16], (const float*)d_in[18],
                          (const float*)d_in[25], (const float*)d_in[27]};
    const float* av[4] = {(const float*)d_in[17], (const float*)d_in[19],
                          (const float*)d_in[26], (const float*)d_in[28]};
    const float* Ws[2] = {(const float*)d_in[20], (const float*)d_in[29]};
    const float* bs[2] = {(const float*)d_in[21], (const float*)d_in[30]};
    const float* vsem[2] = {(const float*)d_in[22], (const float*)d_in[31]};
    const float* Wo[2] = {(const float*)d_in[23], (const float*)d_in[32]};
    const float* bo[2] = {(const float*)d_in[24], (const float*)d_in[33]};
    float* out = (float*)d_out;

    char* p = (char*)d_ws;
    auto carve = [&](size_t bytes) { char* r = p; p += (bytes + 255) & ~(size_t)255; return r; };
    unsigned short* tfb = (unsigned short*)carve((size_t)NNODES * 128 * 2);     // 25.6 MB
    unsigned short* gnb = (unsigned short*)carve((size_t)4 * NTGT * 512 * 2);   // 33.6 MB
    unsigned short* obb = (unsigned short*)carve((size_t)4 * NTGT * 512 * 2);   // 33.6 MB
    unsigned short* hb  = (unsigned short*)carve((size_t)2 * NTGT * 512 * 2);   // 16.8 MB
    unsigned short* w0b = (unsigned short*)carve(65536 * 2);
    unsigned short* w1b = (unsigned short*)carve(65536 * 2);
    unsigned short* wrb = (unsigned short*)carve(4 * 65536 * 2);
    unsigned short* wsb = (unsigned short*)carve(2 * 65536 * 2);
    unsigned short* wob = (unsigned short*)carve(2 * 32768 * 2);
    float* watt4        = (float*)carve(4 * 512 * 4);
    float* ssem         = (float*)carve(4 * 4);
    float* betab        = (float*)carve(4 * 4);
    int* cnt4           = (int*)carve((size_t)4 * NTGT * 4);
    int* rowptr4        = (int*)carve((size_t)4 * (NTGT + 1) * 4);
    int* eids4          = (int*)carve((size_t)4 * NEDGE * 4);

    hipMemsetAsync(ssem, 0, 16, stream);
    hipMemsetAsync(cnt4, 0, (size_t)4 * NTGT * 4, stream);

    dim3 blk(256, 1, 1);

    // pack all weight matrices to bf16 frag-major
    PackArgs pa;
    pa.src[0] = W0; pa.dst[0] = w0b; pa.n16[0] = 8; pa.k32[0] = 16; pa.ld[0] = 512;
    pa.src[1] = W1; pa.dst[1] = w1b; pa.n16[1] = 8; pa.k32[1] = 16; pa.ld[1] = 512;
    for (int mp = 0; mp < 4; ++mp)
        for (int h = 0; h < 4; ++h) {
            int c = 2 + mp * 4 + h;
            pa.src[c] = Wr[mp] + (size_t)h * 128 * 128;
            pa.dst[c] = wrb + (size_t)(mp * 4 + h) * 16384;
            pa.n16[c] = 8; pa.k32[c] = 4; pa.ld[c] = 128;
        }
    pa.src[18] = Ws[0]; pa.dst[18] = wsb;         pa.n16[18] = 8; pa.k32[18] = 16; pa.ld[18] = 512;
    pa.src[19] = Ws[1]; pa.dst[19] = wsb + 65536; pa.n16[19] = 8; pa.k32[19] = 16; pa.ld[19] = 512;
    pa.src[20] = Wo[0]; pa.dst[20] = wob;         pa.n16[20] = 4; pa.k32[20] = 16; pa.ld[20] = 512;
    pa.src[21] = Wo[1]; pa.dst[21] = wob + 32768; pa.n16[21] = 4; pa.k32[21] = 16; pa.ld[21] = 512;
    pack_kernel<<<dim3(32, 22), blk, 0, stream>>>(pa);

    WattArgs wa;
    for (int mp = 0; mp < 4; ++mp) { wa.Wr[mp] = Wr[mp]; wa.a[mp] = av[mp]; }
    watt_kernel<<<dim3(8), blk, 0, stream>>>(wa, watt4);

    // typed node transform -> tfb (bf16), both types in one dispatch
    {
        GArgs g = {};
        g.A[0] = feat0; g.A[1] = feat1;
        g.B[0] = w0b;   g.B[1] = w1b;
        g.bias[0] = b0; g.bias[1] = b1;
        g.C[0] = tfb;   g.C[1] = tfb;
        g.rowmap[0] = nidx0; g.rowmap[1] = nidx1;
        mgemm<0, 8, 2, false, true><<<dim3(391, 1, 2), blk, 0, stream>>>(
            g, 512, 128, 0, 0, 0, 50000, 512);
    }

    EArgs ea;
    for (int mp = 0; mp < 4; ++mp) { ea.eidx[mp] = eidx[mp]; ea.etgt[mp] = etgt[mp]; }

    hist_kernel<<<dim3(391, 4), blk, 0, stream>>>(ea, cnt4, NEDGE);
    scan_kernel<<<dim3(4), blk, 0, stream>>>(cnt4, rowptr4);
    scatter_kernel<<<dim3(391, 4), blk, 0, stream>>>(ea, rowptr4, cnt4, eids4, NEDGE);
    seg_online<<<dim3(NTGT / 4, 4), blk, 0, stream>>>(ea, rowptr4, eids4, tfb, watt4, gnb);

    const size_t LOG_OFF[2] = {0, (size_t)NTGT * 64};
    float* hout = out + (size_t)NTGT * 128;   // h regions: [2][NTGT][512] contiguous

    // EPI1: obb[mp] = elu(gn[mp]_h @ Wr[mp]_h^T) bf16, grid.y = head, grid.z = mp
    {
        GArgs g = {};
        for (int mp = 0; mp < 4; ++mp) {
            g.A[mp] = gnb + (size_t)mp * NTGT * 512;
            g.B[mp] = wrb + (size_t)mp * 65536;
            g.C[mp] = obb + (size_t)mp * NTGT * 512;
        }
        mgemm<1, 8, 2, true, true><<<dim3(64, 4, 4), blk, 0, stream>>>(
            g, 512, 512, 128, 16384, 128, NTGT, 128);
    }

    // EPI2: ssem[mp] += sum tanh(obb[mp] @ Ws^T + bs) . vs
    {
        GArgs g = {};
        for (int mp = 0; mp < 4; ++mp) {
            int nt = mp >> 1;
            g.A[mp] = obb + (size_t)mp * NTGT * 512;
            g.B[mp] = wsb + (size_t)nt * 65536;
            g.bias[mp] = bs[nt];
            g.vs[mp] = vsem[nt];
            g.sem[mp] = ssem + mp;
        }
        mgemm<2, 8, 1, true, false><<<dim3(128, 1, 4), blk, 0, stream>>>(
            g, 512, 0, 0, 0, 0, NTGT, 512);
    }

    beta_kernel<<<dim3(1), dim3(64), 0, stream>>>(ssem, betab);
    combine_kernel<<<dim3(NTGT * 512 / 4 / 256, 2), blk, 0, stream>>>(obb, betab, hout, hb);

    // logits: out[LOG_OFF[nt]] = h[nt] @ Wo[nt]^T + bo[nt]
    {
        GArgs g = {};
        for (int nt = 0; nt < 2; ++nt) {
            g.A[nt] = hb + (size_t)nt * NTGT * 512;
            g.B[nt] = wob + (size_t)nt * 32768;
            g.bias[nt] = bo[nt];
            g.C[nt] = out + LOG_OFF[nt];
        }
        mgemm<0, 4, 1, true, false><<<dim3(128, 1, 2), blk, 0, stream>>>(
            g, 512, 64, 0, 0, 0, NTGT, 512);
    }
}